// Round 11
// baseline (457.925 us; speedup 1.0000x reference)
//
#include <hip/hip_runtime.h>

#define N 100000
#define E 1000000
#define ETOT 1100000   // E + N self-loops
#define NB1 391        // ceil(N/256)
#define NBE 4297       // ceil(ETOT/256)
#define NBG 782        // ceil(N/128) gemm1 blocks

typedef __attribute__((ext_vector_type(8))) short bf16x8;
typedef __attribute__((ext_vector_type(4))) float f32x4;

__device__ __forceinline__ float lrelu(float x) { return x > 0.f ? x : 0.2f * x; }
// f32 -> bf16 bits, round-to-nearest-even
__device__ __forceinline__ unsigned short f2b(float x) {
    unsigned u = __float_as_uint(x);
    return (unsigned short)((u + 0x7FFFu + ((u >> 16) & 1u)) >> 16);
}
__device__ __forceinline__ float b2f(unsigned short v) {
    return __uint_as_float(((unsigned)v) << 16);
}

// ---------------- CSR histogram + weight prep (independent work, one dispatch) ----------------
__global__ __launch_bounds__(256) void prep_kernel(const int* __restrict__ ei,
                                                   int* __restrict__ hist,
                                                   const float* __restrict__ W1,
                                                   const float* __restrict__ W2,
                                                   const float* __restrict__ att_src1,
                                                   const float* __restrict__ att_dst1,
                                                   unsigned short* __restrict__ W1T,
                                                   unsigned short* __restrict__ W2T) {
    const int b = blockIdx.x;
    const int t = threadIdx.x;
    if (b < NBE) {
        const int e = b * 256 + t;
        if (e < ETOT) {
            int d = (e < E) ? ei[E + e] : (e - E);
            atomicAdd(&hist[d], 1);
        }
        return;
    }
    const int bb = b - NBE;
    if (bb < 128) {
        W1T[(size_t)t * 128 + bb] = f2b(W1[(size_t)bb * 256 + t]);
    } else if (bb < 160) {
        int n = bb - 128;
        W2T[(size_t)n * 256 + t] = f2b(W2[(size_t)t * 32 + n]);
    } else {
        int idx = (bb - 160) * 256 + t;         // 0..2047
        int col = idx >> 7;                     // 0..15
        int k = idx & 127;
        int h = col & 7;
        const float* att = (col < 8) ? att_src1 : att_dst1;
        float acc = 0.f;
#pragma unroll 8
        for (int j = 0; j < 32; j++) acc += W1[(size_t)k * 256 + h * 32 + j] * att[h * 32 + j];
        W1T[(size_t)(256 + col) * 128 + k] = f2b(acc);
    }
}

__global__ __launch_bounds__(256) void scan1_kernel(const int* __restrict__ hist,
                                                    int* __restrict__ rofs,
                                                    int* __restrict__ bsum) {
    __shared__ int sm[256];
    const int t = threadIdx.x;
    const int i = blockIdx.x * 256 + t;
    int v = (i < N) ? hist[i] : 0;
    sm[t] = v;
    __syncthreads();
#pragma unroll
    for (int off = 1; off < 256; off <<= 1) {
        int x = (t >= off) ? sm[t - off] : 0;
        __syncthreads();
        sm[t] += x;
        __syncthreads();
    }
    if (i < N) rofs[i] = sm[t] - v;
    if (t == 255) bsum[blockIdx.x] = sm[255];
}

__global__ __launch_bounds__(512) void scan2_kernel(int* __restrict__ bsum) {
    __shared__ int sm[512];
    const int t = threadIdx.x;
    int v = (t < NB1) ? bsum[t] : 0;
    sm[t] = v;
    __syncthreads();
#pragma unroll
    for (int off = 1; off < 512; off <<= 1) {
        int x = (t >= off) ? sm[t - off] : 0;
        __syncthreads();
        sm[t] += x;
        __syncthreads();
    }
    if (t < NB1) bsum[t] = sm[t] - v;
}

__global__ __launch_bounds__(256) void scan3_kernel(int* __restrict__ rofs,
                                                    const int* __restrict__ bsum,
                                                    int* __restrict__ cursor) {
    const int i = blockIdx.x * 256 + threadIdx.x;
    if (i < N) {
        int r = rofs[i] + bsum[blockIdx.x];
        rofs[i] = r;
        cursor[i] = r;
    }
    if (i == 0) rofs[N] = ETOT;
}

// ---------------- fused: scatter (CSR edge placement) + layer-1 GEMM via MFMA ----------------
// blocks 0..NBE-1: scatter; blocks NBE..NBE+NBG-1: gemm1 (independent inputs/outputs)
__global__ __launch_bounds__(256) void sg_kernel(const int* __restrict__ ei,
                                                 int* __restrict__ cursor,
                                                 int* __restrict__ esrc,
                                                 const float* __restrict__ x0,
                                                 const unsigned short* __restrict__ W1T,
                                                 unsigned short* __restrict__ h1,
                                                 float* __restrict__ a_src,
                                                 float* __restrict__ a_dst) {
    if (blockIdx.x < NBE) {
        const int e = blockIdx.x * 256 + threadIdx.x;
        if (e < ETOT) {
            int s, d;
            if (e < E) { s = ei[e]; d = ei[E + e]; } else { s = d = e - E; }
            int pos = atomicAdd(&cursor[d], 1);
            esrc[pos] = s;
        }
        return;
    }
    const int wv = threadIdx.x >> 6;
    const int lane = threadIdx.x & 63;
    const int quad = lane >> 4, c = lane & 15;
    const int base_m = (blockIdx.x - NBE) * 128 + wv * 32;
    bf16x8 af[2][4];
#pragma unroll
    for (int mt = 0; mt < 2; mt++) {
        int row = base_m + mt * 16 + c;
        int rowc = row < N ? row : N - 1;
        const float* ap = x0 + (size_t)rowc * 128 + quad * 8;
#pragma unroll
        for (int ks = 0; ks < 4; ks++) {
            float4 lo = *(const float4*)(ap + ks * 32);
            float4 hi = *(const float4*)(ap + ks * 32 + 4);
            bf16x8 f;
            f[0] = (short)f2b(lo.x); f[1] = (short)f2b(lo.y);
            f[2] = (short)f2b(lo.z); f[3] = (short)f2b(lo.w);
            f[4] = (short)f2b(hi.x); f[5] = (short)f2b(hi.y);
            f[6] = (short)f2b(hi.z); f[7] = (short)f2b(hi.w);
            af[mt][ks] = f;
        }
    }
    for (int nt = 0; nt < 17; nt++) {
        f32x4 acc0 = {0.f, 0.f, 0.f, 0.f};
        f32x4 acc1 = {0.f, 0.f, 0.f, 0.f};
#pragma unroll
        for (int ks = 0; ks < 4; ks++) {
            bf16x8 bf = *(const bf16x8*)(W1T + (size_t)(nt * 16 + c) * 128 + ks * 32 + quad * 8);
            acc0 = __builtin_amdgcn_mfma_f32_16x16x32_bf16(af[0][ks], bf, acc0, 0, 0, 0);
            acc1 = __builtin_amdgcn_mfma_f32_16x16x32_bf16(af[1][ks], bf, acc1, 0, 0, 0);
        }
        if (nt < 16) {
            const int col = nt * 16 + c;
#pragma unroll
            for (int r = 0; r < 4; r++) {
                int row0 = base_m + quad * 4 + r;
                if (row0 < N) h1[(size_t)row0 * 256 + col] = f2b(acc0[r]);
                int row1 = base_m + 16 + quad * 4 + r;
                if (row1 < N) h1[(size_t)row1 * 256 + col] = f2b(acc1[r]);
            }
        } else {
            float* dst = (c < 8) ? a_src : a_dst;
            int hh = c & 7;
#pragma unroll
            for (int r = 0; r < 4; r++) {
                int row0 = base_m + quad * 4 + r;
                if (row0 < N) dst[(size_t)row0 * 8 + hh] = acc0[r];
                int row1 = base_m + 16 + quad * 4 + r;
                if (row1 < N) dst[(size_t)row1 * 8 + hh] = acc1[r];
            }
        }
    }
}

// ---------------- layer 1 aggregate v4: wave/node; 1 exp per 8 edges; 8 gathers in flight ----------------
__global__ __launch_bounds__(256) void seg1_kernel(const int* __restrict__ esrc,
                                                   const int* __restrict__ rofs,
                                                   const float* __restrict__ a_src,
                                                   const float* __restrict__ a_dst,
                                                   const unsigned short* __restrict__ h1,
                                                   const float* __restrict__ b1,
                                                   unsigned short* __restrict__ x2) {
    const int n = (blockIdx.x * 256 + threadIdx.x) >> 6;   // wave-uniform node
    const int lane = threadIdx.x & 63;
    const int e_pa = lane >> 3;          // phase-A edge slot 0..7
    const int h_pa = lane & 7;           // phase-A head
    const int hB = lane >> 3;            // phase-B/epilogue head
    const int rs = __builtin_amdgcn_readfirstlane(rofs[n]);
    const int re = __builtin_amdgcn_readfirstlane(rofs[n + 1]);
    const float ad_pa = a_dst[(size_t)n * 8 + h_pa];
    float dsum = 0.f;
    float4 Aa = {0, 0, 0, 0}, Ab = {0, 0, 0, 0};
    for (int j0 = rs; j0 < re; j0 += 8) {
        // phase A: weights for 8 edges x 8 heads, ONE v_exp
        int jm = j0 + e_pa;
        int jc = jm < re ? jm : re - 1;
        int s8 = esrc[jc];
        float av = a_src[(size_t)s8 * 8 + h_pa];
        float ex = __expf(lrelu(av + ad_pa));
        float w = (jm < re) ? ex : 0.f;
        dsum += w;
        // phase B: all 8 gathers issue unconditionally (dead edges clamp to re-1, w=0 masks)
#pragma unroll
        for (int e = 0; e < 8; e++) {
            float wb = __shfl(w, e * 8 + hB, 64);
            int se = __builtin_amdgcn_readlane(s8, e * 8);
            ushort4 hb = ((const ushort4*)(h1 + (size_t)se * 256))[lane];
            if (e & 1) {
                Ab.x += wb * b2f(hb.x); Ab.y += wb * b2f(hb.y);
                Ab.z += wb * b2f(hb.z); Ab.w += wb * b2f(hb.w);
            } else {
                Aa.x += wb * b2f(hb.x); Aa.y += wb * b2f(hb.y);
                Aa.z += wb * b2f(hb.z); Aa.w += wb * b2f(hb.w);
            }
        }
    }
    // reduce dsum over the 8 edge slots
    dsum += __shfl_xor(dsum, 8, 64);
    dsum += __shfl_xor(dsum, 16, 64);
    dsum += __shfl_xor(dsum, 32, 64);
    float den = __shfl(dsum, hB, 64);    // lane L<8 holds den for head L
    float4 acc = {Aa.x + Ab.x, Aa.y + Ab.y, Aa.z + Ab.z, Aa.w + Ab.w};
    const float inv = 1.0f / den;
    float4 bb = ((const float4*)b1)[lane];
    float vx = acc.x * inv + bb.x, vy = acc.y * inv + bb.y;
    float vz = acc.z * inv + bb.z, vw = acc.w * inv + bb.w;
    vx = vx > 0.f ? vx : 0.f; vy = vy > 0.f ? vy : 0.f;
    vz = vz > 0.f ? vz : 0.f; vw = vw > 0.f ? vw : 0.f;
    ushort4 o = {f2b(vx), f2b(vy), f2b(vz), f2b(vw)};
    ((ushort4*)(x2 + (size_t)n * 256))[lane] = o;
}

// ---------------- layer 2 GEMM via MFMA: h2 = x2 @ W2 (256->32), fused logits ----------------
__global__ __launch_bounds__(256) void gemm2_kernel(const unsigned short* __restrict__ x2,
                                                    const unsigned short* __restrict__ W2T,
                                                    const float* __restrict__ att_src2,
                                                    const float* __restrict__ att_dst2,
                                                    unsigned short* __restrict__ h2,
                                                    float* __restrict__ a_src2,
                                                    float* __restrict__ a_dst2) {
    const int wv = threadIdx.x >> 6;
    const int lane = threadIdx.x & 63;
    const int quad = lane >> 4, c = lane & 15;
    const int base_m = blockIdx.x * 128 + wv * 32;
    f32x4 acc[2][2] = {{{0, 0, 0, 0}, {0, 0, 0, 0}}, {{0, 0, 0, 0}, {0, 0, 0, 0}}};
#pragma unroll
    for (int ks = 0; ks < 8; ks++) {
        bf16x8 b0 = *(const bf16x8*)(W2T + (size_t)c * 256 + ks * 32 + quad * 8);
        bf16x8 b1 = *(const bf16x8*)(W2T + (size_t)(16 + c) * 256 + ks * 32 + quad * 8);
#pragma unroll
        for (int mt = 0; mt < 2; mt++) {
            int row = base_m + mt * 16 + c;
            int rowc = row < N ? row : N - 1;
            bf16x8 a = *(const bf16x8*)(x2 + (size_t)rowc * 256 + ks * 32 + quad * 8);
            acc[mt][0] = __builtin_amdgcn_mfma_f32_16x16x32_bf16(a, b0, acc[mt][0], 0, 0, 0);
            acc[mt][1] = __builtin_amdgcn_mfma_f32_16x16x32_bf16(a, b1, acc[mt][1], 0, 0, 0);
        }
    }
    float as0 = att_src2[c], as1 = att_src2[16 + c];
    float ad0 = att_dst2[c], ad1 = att_dst2[16 + c];
#pragma unroll
    for (int mt = 0; mt < 2; mt++) {
#pragma unroll
        for (int r = 0; r < 4; r++) {
            int row = base_m + mt * 16 + quad * 4 + r;
            float v0 = acc[mt][0][r], v1 = acc[mt][1][r];
            float ps = v0 * as0 + v1 * as1;
            float pd = v0 * ad0 + v1 * ad1;
#pragma unroll
            for (int off = 1; off < 16; off <<= 1) {
                ps += __shfl_xor(ps, off, 64);
                pd += __shfl_xor(pd, off, 64);
            }
            if (row < N) {
                h2[(size_t)row * 32 + c] = f2b(v0);
                h2[(size_t)row * 32 + 16 + c] = f2b(v1);
                if (c == 0) { a_src2[row] = ps; a_dst2[row] = pd; }
            }
        }
    }
}

// ---------------- layer 2 aggregate + final linear fused: half-wave/node, masked 8 chains (R9 form) ----------------
__global__ __launch_bounds__(256) void seg2_kernel(const int* __restrict__ esrc,
                                                   const int* __restrict__ rofs,
                                                   const float* __restrict__ a_src2,
                                                   const float* __restrict__ a_dst2,
                                                   const unsigned short* __restrict__ h2,
                                                   const float* __restrict__ b2,
                                                   const float* __restrict__ linW,
                                                   const float* __restrict__ linb,
                                                   float* __restrict__ out) {
    __shared__ float lws[32 * 40];
    __shared__ float vbuf[8][32];
    const int t = threadIdx.x;
    for (int i = t; i < 1280; i += 256) lws[i] = linW[i];
    const int n8 = t >> 5;
    const int c = t & 31;
    const int n = blockIdx.x * 8 + n8;      // N % 8 == 0 -> always valid
    const int rs = rofs[n], re = rofs[n + 1];
    const float ad = a_dst2[n];
    float d[8] = {0, 0, 0, 0, 0, 0, 0, 0};
    float A[8] = {0, 0, 0, 0, 0, 0, 0, 0};
    for (int j0 = rs; j0 < re; j0 += 8) {
        int sidx[8];
#pragma unroll
        for (int k = 0; k < 8; k++) {
            int j = j0 + k;
            sidx[k] = esrc[j < re ? j : re - 1];
        }
        unsigned short hb[8];
        float as[8];
#pragma unroll
        for (int k = 0; k < 8; k++) {
            hb[k] = h2[(size_t)sidx[k] * 32 + c];
            as[k] = a_src2[sidx[k]];
        }
#pragma unroll
        for (int k = 0; k < 8; k++) {
            float w = (j0 + k < re) ? __expf(lrelu(as[k] + ad)) : 0.f;
            d[k] += w;
            A[k] += w * b2f(hb[k]);
        }
    }
    float den = ((d[0] + d[1]) + (d[2] + d[3])) + ((d[4] + d[5]) + (d[6] + d[7]));
    float acc = ((A[0] + A[1]) + (A[2] + A[3])) + ((A[4] + A[5]) + (A[6] + A[7]));
    vbuf[n8][c] = acc / den + b2[c];
    __syncthreads();
    for (int idx = t; idx < 320; idx += 256) {
        int nn = idx / 40, o = idx - nn * 40;
        float s = linb[o];
#pragma unroll
        for (int ci = 0; ci < 32; ci++) s += vbuf[nn][ci] * lws[ci * 40 + o];
        out[(size_t)blockIdx.x * 320 + idx] = s;
    }
}

extern "C" void kernel_launch(void* const* d_in, const int* in_sizes, int n_in,
                              void* d_out, int out_size, void* d_ws, size_t ws_size,
                              hipStream_t stream) {
    const float* x0       = (const float*)d_in[0];
    const float* W1       = (const float*)d_in[1];
    const float* att_src1 = (const float*)d_in[2];
    const float* att_dst1 = (const float*)d_in[3];
    const float* b1       = (const float*)d_in[4];
    const float* W2       = (const float*)d_in[5];
    const float* att_src2 = (const float*)d_in[6];
    const float* att_dst2 = (const float*)d_in[7];
    const float* b2       = (const float*)d_in[8];
    const float* linW     = (const float*)d_in[9];
    const float* linb     = (const float*)d_in[10];
    const int*   ei       = (const int*)d_in[11];
    float* out = (float*)d_out;
    float* ws  = (float*)d_ws;

    unsigned short* h1   = (unsigned short*)ws;                  // 25.6M bf16 = 12.8M floats
    unsigned short* x2   = (unsigned short*)(ws + 12800000);     // 25.6M bf16
    float* a_src1        = ws + 25600000;                        // 0.8M
    float* a_dst1        = ws + 26400000;                        // 0.8M
    unsigned short* h2   = (unsigned short*)(ws + 27200000);     // 3.2M bf16
    float* a_src2        = ws + 28800000;                        // 0.1M
    float* a_dst2        = ws + 28900000;                        // 0.1M
    unsigned short* W1T  = (unsigned short*)(ws + 29000000);     // 272*128 bf16
    unsigned short* W2T  = (unsigned short*)(ws + 29020000);     // 32*256 bf16
    int*   hist          = (int*)(ws + 29030000);                // 0.1M
    int*   rofs          = (int*)(ws + 29130000);                // N+1
    int*   cursor        = (int*)(ws + 29240000);                // 0.1M
    int*   bsum          = (int*)(ws + 29340000);                // 512
    int*   esrc          = (int*)(ws + 29341000);                // 1.1M

    hipMemsetAsync(hist, 0, (size_t)N * 4, stream);

    prep_kernel<<<NBE + 168, 256, 0, stream>>>(ei, hist, W1, W2, att_src1, att_dst1, W1T, W2T);
    scan1_kernel<<<NB1, 256, 0, stream>>>(hist, rofs, bsum);
    scan2_kernel<<<1, 512, 0, stream>>>(bsum);
    scan3_kernel<<<NB1, 256, 0, stream>>>(rofs, bsum, cursor);

    // fused scatter + gemm1 (independent work, overlapped in one dispatch)
    sg_kernel<<<NBE + NBG, 256, 0, stream>>>(ei, cursor, esrc, x0, W1T, h1, a_src1, a_dst1);

    seg1_kernel<<<N / 4, 256, 0, stream>>>(esrc, rofs, a_src1, a_dst1, h1, b1, x2);
    gemm2_kernel<<<(N + 127) / 128, 256, 0, stream>>>(x2, W2T, att_src2, att_dst2, h2, a_src2, a_dst2);
    seg2_kernel<<<N / 8, 256, 0, stream>>>(esrc, rofs, a_src2, a_dst2, h2, b2, linW, linb, out);
}

// Round 12
// 432.338 us; speedup vs baseline: 1.0592x; 1.0592x over previous
//
#include <hip/hip_runtime.h>

#define N 100000
#define E 1000000
#define ETOT 1100000   // E + N self-loops
#define NB1 391        // ceil(N/256)
#define NBE 4297       // ceil(ETOT/256)
#define NBG 782        // ceil(N/128) gemm1 blocks

typedef __attribute__((ext_vector_type(8))) short bf16x8;
typedef __attribute__((ext_vector_type(4))) float f32x4;

__device__ __forceinline__ float lrelu(float x) { return x > 0.f ? x : 0.2f * x; }
// f32 -> bf16 bits, round-to-nearest-even
__device__ __forceinline__ unsigned short f2b(float x) {
    unsigned u = __float_as_uint(x);
    return (unsigned short)((u + 0x7FFFu + ((u >> 16) & 1u)) >> 16);
}
__device__ __forceinline__ float b2f(unsigned short v) {
    return __uint_as_float(((unsigned)v) << 16);
}

// ---------------- CSR histogram + weight prep (independent work, one dispatch) ----------------
__global__ __launch_bounds__(256) void prep_kernel(const int* __restrict__ ei,
                                                   int* __restrict__ hist,
                                                   const float* __restrict__ W1,
                                                   const float* __restrict__ W2,
                                                   const float* __restrict__ att_src1,
                                                   const float* __restrict__ att_dst1,
                                                   unsigned short* __restrict__ W1T,
                                                   unsigned short* __restrict__ W2T) {
    const int b = blockIdx.x;
    const int t = threadIdx.x;
    if (b < NBE) {
        const int e = b * 256 + t;
        if (e < ETOT) {
            int d = (e < E) ? ei[E + e] : (e - E);
            atomicAdd(&hist[d], 1);
        }
        return;
    }
    const int bb = b - NBE;
    if (bb < 128) {
        W1T[(size_t)t * 128 + bb] = f2b(W1[(size_t)bb * 256 + t]);
    } else if (bb < 160) {
        int n = bb - 128;
        W2T[(size_t)n * 256 + t] = f2b(W2[(size_t)t * 32 + n]);
    } else {
        int idx = (bb - 160) * 256 + t;         // 0..2047
        int col = idx >> 7;                     // 0..15
        int k = idx & 127;
        int h = col & 7;
        const float* att = (col < 8) ? att_src1 : att_dst1;
        float acc = 0.f;
#pragma unroll 8
        for (int j = 0; j < 32; j++) acc += W1[(size_t)k * 256 + h * 32 + j] * att[h * 32 + j];
        W1T[(size_t)(256 + col) * 128 + k] = f2b(acc);
    }
}

// ---------------- merged: layer-1 GEMM (blocks 0..NBG-1) + scan1 (blocks NBG..NBG+NB1-1) ----------------
// Both depend only on prep. scan1 is tiny, atomic-free, no L2 working set -> safe to co-schedule.
__global__ __launch_bounds__(256) void g1s_kernel(const float* __restrict__ x0,
                                                  const unsigned short* __restrict__ W1T,
                                                  unsigned short* __restrict__ h1,
                                                  float* __restrict__ a_src,
                                                  float* __restrict__ a_dst,
                                                  const int* __restrict__ hist,
                                                  int* __restrict__ rofs,
                                                  int* __restrict__ bsum) {
    __shared__ int sm[256];
    if (blockIdx.x >= NBG) {
        // ---- scan1: block-local exclusive scan of hist ----
        const int blk = blockIdx.x - NBG;
        const int t = threadIdx.x;
        const int i = blk * 256 + t;
        int v = (i < N) ? hist[i] : 0;
        sm[t] = v;
        __syncthreads();
#pragma unroll
        for (int off = 1; off < 256; off <<= 1) {
            int x = (t >= off) ? sm[t - off] : 0;
            __syncthreads();
            sm[t] += x;
            __syncthreads();
        }
        if (i < N) rofs[i] = sm[t] - v;
        if (t == 255) bsum[blk] = sm[255];
        return;
    }
    // ---- gemm1: h1 = x0 @ W1 (+ fused logits via fold tile) ----
    const int wv = threadIdx.x >> 6;
    const int lane = threadIdx.x & 63;
    const int quad = lane >> 4, c = lane & 15;
    const int base_m = blockIdx.x * 128 + wv * 32;
    bf16x8 af[2][4];
#pragma unroll
    for (int mt = 0; mt < 2; mt++) {
        int row = base_m + mt * 16 + c;
        int rowc = row < N ? row : N - 1;
        const float* ap = x0 + (size_t)rowc * 128 + quad * 8;
#pragma unroll
        for (int ks = 0; ks < 4; ks++) {
            float4 lo = *(const float4*)(ap + ks * 32);
            float4 hi = *(const float4*)(ap + ks * 32 + 4);
            bf16x8 f;
            f[0] = (short)f2b(lo.x); f[1] = (short)f2b(lo.y);
            f[2] = (short)f2b(lo.z); f[3] = (short)f2b(lo.w);
            f[4] = (short)f2b(hi.x); f[5] = (short)f2b(hi.y);
            f[6] = (short)f2b(hi.z); f[7] = (short)f2b(hi.w);
            af[mt][ks] = f;
        }
    }
    for (int nt = 0; nt < 17; nt++) {
        f32x4 acc0 = {0.f, 0.f, 0.f, 0.f};
        f32x4 acc1 = {0.f, 0.f, 0.f, 0.f};
#pragma unroll
        for (int ks = 0; ks < 4; ks++) {
            bf16x8 bf = *(const bf16x8*)(W1T + (size_t)(nt * 16 + c) * 128 + ks * 32 + quad * 8);
            acc0 = __builtin_amdgcn_mfma_f32_16x16x32_bf16(af[0][ks], bf, acc0, 0, 0, 0);
            acc1 = __builtin_amdgcn_mfma_f32_16x16x32_bf16(af[1][ks], bf, acc1, 0, 0, 0);
        }
        if (nt < 16) {
            const int col = nt * 16 + c;
#pragma unroll
            for (int r = 0; r < 4; r++) {
                int row0 = base_m + quad * 4 + r;
                if (row0 < N) h1[(size_t)row0 * 256 + col] = f2b(acc0[r]);
                int row1 = base_m + 16 + quad * 4 + r;
                if (row1 < N) h1[(size_t)row1 * 256 + col] = f2b(acc1[r]);
            }
        } else {
            float* dst = (c < 8) ? a_src : a_dst;
            int hh = c & 7;
#pragma unroll
            for (int r = 0; r < 4; r++) {
                int row0 = base_m + quad * 4 + r;
                if (row0 < N) dst[(size_t)row0 * 8 + hh] = acc0[r];
                int row1 = base_m + 16 + quad * 4 + r;
                if (row1 < N) dst[(size_t)row1 * 8 + hh] = acc1[r];
            }
        }
    }
}

__global__ __launch_bounds__(512) void scan2_kernel(int* __restrict__ bsum) {
    __shared__ int sm[512];
    const int t = threadIdx.x;
    int v = (t < NB1) ? bsum[t] : 0;
    sm[t] = v;
    __syncthreads();
#pragma unroll
    for (int off = 1; off < 512; off <<= 1) {
        int x = (t >= off) ? sm[t - off] : 0;
        __syncthreads();
        sm[t] += x;
        __syncthreads();
    }
    if (t < NB1) bsum[t] = sm[t] - v;
}

__global__ __launch_bounds__(256) void scan3_kernel(int* __restrict__ rofs,
                                                    const int* __restrict__ bsum,
                                                    int* __restrict__ cursor) {
    const int i = blockIdx.x * 256 + threadIdx.x;
    if (i < N) {
        int r = rofs[i] + bsum[blockIdx.x];
        rofs[i] = r;
        cursor[i] = r;
    }
    if (i == 0) rofs[N] = ETOT;
}

// scatter stays SOLO: its cursor/esrc working set must own the L2 (R11 lesson)
__global__ __launch_bounds__(256) void scatter_kernel(const int* __restrict__ ei,
                                                      int* __restrict__ cursor,
                                                      int* __restrict__ esrc) {
    const int e = blockIdx.x * 256 + threadIdx.x;
    if (e >= ETOT) return;
    int s, d;
    if (e < E) { s = ei[e]; d = ei[E + e]; } else { s = d = e - E; }
    int pos = atomicAdd(&cursor[d], 1);
    esrc[pos] = s;
}

// ---------------- layer 1 aggregate v4: wave/node; 1 exp per 8 edges; 8 gathers in flight ----------------
__global__ __launch_bounds__(256) void seg1_kernel(const int* __restrict__ esrc,
                                                   const int* __restrict__ rofs,
                                                   const float* __restrict__ a_src,
                                                   const float* __restrict__ a_dst,
                                                   const unsigned short* __restrict__ h1,
                                                   const float* __restrict__ b1,
                                                   unsigned short* __restrict__ x2) {
    const int n = (blockIdx.x * 256 + threadIdx.x) >> 6;   // wave-uniform node
    const int lane = threadIdx.x & 63;
    const int e_pa = lane >> 3;          // phase-A edge slot 0..7
    const int h_pa = lane & 7;           // phase-A head
    const int hB = lane >> 3;            // phase-B/epilogue head
    const int rs = __builtin_amdgcn_readfirstlane(rofs[n]);
    const int re = __builtin_amdgcn_readfirstlane(rofs[n + 1]);
    const float ad_pa = a_dst[(size_t)n * 8 + h_pa];
    float dsum = 0.f;
    float4 Aa = {0, 0, 0, 0}, Ab = {0, 0, 0, 0};
    for (int j0 = rs; j0 < re; j0 += 8) {
        // phase A: weights for 8 edges x 8 heads, ONE v_exp
        int jm = j0 + e_pa;
        int jc = jm < re ? jm : re - 1;
        int s8 = esrc[jc];
        float av = a_src[(size_t)s8 * 8 + h_pa];
        float ex = __expf(lrelu(av + ad_pa));
        float w = (jm < re) ? ex : 0.f;
        dsum += w;
        // phase B: all 8 gathers issue unconditionally (dead edges clamp to re-1, w=0 masks)
#pragma unroll
        for (int e = 0; e < 8; e++) {
            float wb = __shfl(w, e * 8 + hB, 64);
            int se = __builtin_amdgcn_readlane(s8, e * 8);
            ushort4 hb = ((const ushort4*)(h1 + (size_t)se * 256))[lane];
            if (e & 1) {
                Ab.x += wb * b2f(hb.x); Ab.y += wb * b2f(hb.y);
                Ab.z += wb * b2f(hb.z); Ab.w += wb * b2f(hb.w);
            } else {
                Aa.x += wb * b2f(hb.x); Aa.y += wb * b2f(hb.y);
                Aa.z += wb * b2f(hb.z); Aa.w += wb * b2f(hb.w);
            }
        }
    }
    // reduce dsum over the 8 edge slots
    dsum += __shfl_xor(dsum, 8, 64);
    dsum += __shfl_xor(dsum, 16, 64);
    dsum += __shfl_xor(dsum, 32, 64);
    float den = __shfl(dsum, hB, 64);    // lane L<8 holds den for head L
    float4 acc = {Aa.x + Ab.x, Aa.y + Ab.y, Aa.z + Ab.z, Aa.w + Ab.w};
    const float inv = 1.0f / den;
    float4 bb = ((const float4*)b1)[lane];
    float vx = acc.x * inv + bb.x, vy = acc.y * inv + bb.y;
    float vz = acc.z * inv + bb.z, vw = acc.w * inv + bb.w;
    vx = vx > 0.f ? vx : 0.f; vy = vy > 0.f ? vy : 0.f;
    vz = vz > 0.f ? vz : 0.f; vw = vw > 0.f ? vw : 0.f;
    ushort4 o = {f2b(vx), f2b(vy), f2b(vz), f2b(vw)};
    ((ushort4*)(x2 + (size_t)n * 256))[lane] = o;
}

// ---------------- layer 2 GEMM via MFMA: h2 = x2 @ W2 (256->32), fused logits ----------------
__global__ __launch_bounds__(256) void gemm2_kernel(const unsigned short* __restrict__ x2,
                                                    const unsigned short* __restrict__ W2T,
                                                    const float* __restrict__ att_src2,
                                                    const float* __restrict__ att_dst2,
                                                    unsigned short* __restrict__ h2,
                                                    float* __restrict__ a_src2,
                                                    float* __restrict__ a_dst2) {
    const int wv = threadIdx.x >> 6;
    const int lane = threadIdx.x & 63;
    const int quad = lane >> 4, c = lane & 15;
    const int base_m = blockIdx.x * 128 + wv * 32;
    f32x4 acc[2][2] = {{{0, 0, 0, 0}, {0, 0, 0, 0}}, {{0, 0, 0, 0}, {0, 0, 0, 0}}};
#pragma unroll
    for (int ks = 0; ks < 8; ks++) {
        bf16x8 b0 = *(const bf16x8*)(W2T + (size_t)c * 256 + ks * 32 + quad * 8);
        bf16x8 b1 = *(const bf16x8*)(W2T + (size_t)(16 + c) * 256 + ks * 32 + quad * 8);
#pragma unroll
        for (int mt = 0; mt < 2; mt++) {
            int row = base_m + mt * 16 + c;
            int rowc = row < N ? row : N - 1;
            bf16x8 a = *(const bf16x8*)(x2 + (size_t)rowc * 256 + ks * 32 + quad * 8);
            acc[mt][0] = __builtin_amdgcn_mfma_f32_16x16x32_bf16(a, b0, acc[mt][0], 0, 0, 0);
            acc[mt][1] = __builtin_amdgcn_mfma_f32_16x16x32_bf16(a, b1, acc[mt][1], 0, 0, 0);
        }
    }
    float as0 = att_src2[c], as1 = att_src2[16 + c];
    float ad0 = att_dst2[c], ad1 = att_dst2[16 + c];
#pragma unroll
    for (int mt = 0; mt < 2; mt++) {
#pragma unroll
        for (int r = 0; r < 4; r++) {
            int row = base_m + mt * 16 + quad * 4 + r;
            float v0 = acc[mt][0][r], v1 = acc[mt][1][r];
            float ps = v0 * as0 + v1 * as1;
            float pd = v0 * ad0 + v1 * ad1;
#pragma unroll
            for (int off = 1; off < 16; off <<= 1) {
                ps += __shfl_xor(ps, off, 64);
                pd += __shfl_xor(pd, off, 64);
            }
            if (row < N) {
                h2[(size_t)row * 32 + c] = f2b(v0);
                h2[(size_t)row * 32 + 16 + c] = f2b(v1);
                if (c == 0) { a_src2[row] = ps; a_dst2[row] = pd; }
            }
        }
    }
}

// ---------------- layer 2 aggregate + final linear fused: half-wave/node, masked 8 chains (R9 form) ----------------
__global__ __launch_bounds__(256) void seg2_kernel(const int* __restrict__ esrc,
                                                   const int* __restrict__ rofs,
                                                   const float* __restrict__ a_src2,
                                                   const float* __restrict__ a_dst2,
                                                   const unsigned short* __restrict__ h2,
                                                   const float* __restrict__ b2,
                                                   const float* __restrict__ linW,
                                                   const float* __restrict__ linb,
                                                   float* __restrict__ out) {
    __shared__ float lws[32 * 40];
    __shared__ float vbuf[8][32];
    const int t = threadIdx.x;
    for (int i = t; i < 1280; i += 256) lws[i] = linW[i];
    const int n8 = t >> 5;
    const int c = t & 31;
    const int n = blockIdx.x * 8 + n8;      // N % 8 == 0 -> always valid
    const int rs = rofs[n], re = rofs[n + 1];
    const float ad = a_dst2[n];
    float d[8] = {0, 0, 0, 0, 0, 0, 0, 0};
    float A[8] = {0, 0, 0, 0, 0, 0, 0, 0};
    for (int j0 = rs; j0 < re; j0 += 8) {
        int sidx[8];
#pragma unroll
        for (int k = 0; k < 8; k++) {
            int j = j0 + k;
            sidx[k] = esrc[j < re ? j : re - 1];
        }
        unsigned short hb[8];
        float as[8];
#pragma unroll
        for (int k = 0; k < 8; k++) {
            hb[k] = h2[(size_t)sidx[k] * 32 + c];
            as[k] = a_src2[sidx[k]];
        }
#pragma unroll
        for (int k = 0; k < 8; k++) {
            float w = (j0 + k < re) ? __expf(lrelu(as[k] + ad)) : 0.f;
            d[k] += w;
            A[k] += w * b2f(hb[k]);
        }
    }
    float den = ((d[0] + d[1]) + (d[2] + d[3])) + ((d[4] + d[5]) + (d[6] + d[7]));
    float acc = ((A[0] + A[1]) + (A[2] + A[3])) + ((A[4] + A[5]) + (A[6] + A[7]));
    vbuf[n8][c] = acc / den + b2[c];
    __syncthreads();
    for (int idx = t; idx < 320; idx += 256) {
        int nn = idx / 40, o = idx - nn * 40;
        float s = linb[o];
#pragma unroll
        for (int ci = 0; ci < 32; ci++) s += vbuf[nn][ci] * lws[ci * 40 + o];
        out[(size_t)blockIdx.x * 320 + idx] = s;
    }
}

extern "C" void kernel_launch(void* const* d_in, const int* in_sizes, int n_in,
                              void* d_out, int out_size, void* d_ws, size_t ws_size,
                              hipStream_t stream) {
    const float* x0       = (const float*)d_in[0];
    const float* W1       = (const float*)d_in[1];
    const float* att_src1 = (const float*)d_in[2];
    const float* att_dst1 = (const float*)d_in[3];
    const float* b1       = (const float*)d_in[4];
    const float* W2       = (const float*)d_in[5];
    const float* att_src2 = (const float*)d_in[6];
    const float* att_dst2 = (const float*)d_in[7];
    const float* b2       = (const float*)d_in[8];
    const float* linW     = (const float*)d_in[9];
    const float* linb     = (const float*)d_in[10];
    const int*   ei       = (const int*)d_in[11];
    float* out = (float*)d_out;
    float* ws  = (float*)d_ws;

    unsigned short* h1   = (unsigned short*)ws;                  // 25.6M bf16 = 12.8M floats
    unsigned short* x2   = (unsigned short*)(ws + 12800000);     // 25.6M bf16
    float* a_src1        = ws + 25600000;                        // 0.8M
    float* a_dst1        = ws + 26400000;                        // 0.8M
    unsigned short* h2   = (unsigned short*)(ws + 27200000);     // 3.2M bf16
    float* a_src2        = ws + 28800000;                        // 0.1M
    float* a_dst2        = ws + 28900000;                        // 0.1M
    unsigned short* W1T  = (unsigned short*)(ws + 29000000);     // 272*128 bf16
    unsigned short* W2T  = (unsigned short*)(ws + 29020000);     // 32*256 bf16
    int*   hist          = (int*)(ws + 29030000);                // 0.1M
    int*   rofs          = (int*)(ws + 29130000);                // N+1
    int*   cursor        = (int*)(ws + 29240000);                // 0.1M
    int*   bsum          = (int*)(ws + 29340000);                // 512
    int*   esrc          = (int*)(ws + 29341000);                // 1.1M

    hipMemsetAsync(hist, 0, (size_t)N * 4, stream);

    prep_kernel<<<NBE + 168, 256, 0, stream>>>(ei, hist, W1, W2, att_src1, att_dst1, W1T, W2T);
    // merged gemm1 + scan1 (both depend only on prep; scan1 is atomic-free and tiny)
    g1s_kernel<<<NBG + NB1, 256, 0, stream>>>(x0, W1T, h1, a_src1, a_dst1, hist, rofs, bsum);
    scan2_kernel<<<1, 512, 0, stream>>>(bsum);
    scan3_kernel<<<NB1, 256, 0, stream>>>(rofs, bsum, cursor);
    scatter_kernel<<<(ETOT + 255) / 256, 256, 0, stream>>>(ei, cursor, esrc);

    seg1_kernel<<<N / 4, 256, 0, stream>>>(esrc, rofs, a_src1, a_dst1, h1, b1, x2);
    gemm2_kernel<<<(N + 127) / 128, 256, 0, stream>>>(x2, W2T, att_src2, att_dst2, h2, a_src2, a_dst2);
    seg2_kernel<<<N / 8, 256, 0, stream>>>(esrc, rofs, a_src2, a_dst2, h2, b2, linW, linb, out);
}

// Round 13
// 401.904 us; speedup vs baseline: 1.1394x; 1.0757x over previous
//
#include <hip/hip_runtime.h>

#define N 100000
#define E 1000000
#define ETOT 1100000   // E + N self-loops
#define NB1 391        // ceil(N/256)
#define NBE 4297       // ceil(ETOT/256)
#define NBG 782        // ceil(N/128) gemm1 blocks

typedef __attribute__((ext_vector_type(8))) short bf16x8;
typedef __attribute__((ext_vector_type(4))) float f32x4;
typedef __attribute__((ext_vector_type(2))) float f32x2;

__device__ __forceinline__ float lrelu(float x) { return x > 0.f ? x : 0.2f * x; }
// f32 -> bf16 bits, round-to-nearest-even
__device__ __forceinline__ unsigned short f2b(float x) {
    unsigned u = __float_as_uint(x);
    return (unsigned short)((u + 0x7FFFu + ((u >> 16) & 1u)) >> 16);
}
__device__ __forceinline__ float b2f(unsigned short v) {
    return __uint_as_float(((unsigned)v) << 16);
}
// f32 -> fp8 e4m3 (OCP), HW round-to-nearest-even
__device__ __forceinline__ unsigned char f2q(float x) {
    return (unsigned char)(__builtin_amdgcn_cvt_pk_fp8_f32(x, x, 0, false) & 0xFF);
}

// ---------------- CSR histogram + weight prep (independent work, one dispatch) ----------------
__global__ __launch_bounds__(256) void prep_kernel(const int* __restrict__ ei,
                                                   int* __restrict__ hist,
                                                   const float* __restrict__ W1,
                                                   const float* __restrict__ W2,
                                                   const float* __restrict__ att_src1,
                                                   const float* __restrict__ att_dst1,
                                                   unsigned short* __restrict__ W1T,
                                                   unsigned short* __restrict__ W2T) {
    const int b = blockIdx.x;
    const int t = threadIdx.x;
    if (b < NBE) {
        const int e = b * 256 + t;
        if (e < ETOT) {
            int d = (e < E) ? ei[E + e] : (e - E);
            atomicAdd(&hist[d], 1);
        }
        return;
    }
    const int bb = b - NBE;
    if (bb < 128) {
        W1T[(size_t)t * 128 + bb] = f2b(W1[(size_t)bb * 256 + t]);
    } else if (bb < 160) {
        int n = bb - 128;
        W2T[(size_t)n * 256 + t] = f2b(W2[(size_t)t * 32 + n]);
    } else {
        int idx = (bb - 160) * 256 + t;         // 0..2047
        int col = idx >> 7;                     // 0..15
        int k = idx & 127;
        int h = col & 7;
        const float* att = (col < 8) ? att_src1 : att_dst1;
        float acc = 0.f;
#pragma unroll 8
        for (int j = 0; j < 32; j++) acc += W1[(size_t)k * 256 + h * 32 + j] * att[h * 32 + j];
        W1T[(size_t)(256 + col) * 128 + k] = f2b(acc);
    }
}

// ---------------- merged: layer-1 GEMM (blocks 0..NBG-1) + scan1 (blocks NBG..) ----------------
// h1 is stored fp8 e4m3 (storage-only quantization; f32 accumulate downstream)
__global__ __launch_bounds__(256) void g1s_kernel(const float* __restrict__ x0,
                                                  const unsigned short* __restrict__ W1T,
                                                  unsigned char* __restrict__ h1,
                                                  float* __restrict__ a_src,
                                                  float* __restrict__ a_dst,
                                                  const int* __restrict__ hist,
                                                  int* __restrict__ rofs,
                                                  int* __restrict__ bsum) {
    __shared__ int sm[256];
    if (blockIdx.x >= NBG) {
        // ---- scan1: block-local exclusive scan of hist ----
        const int blk = blockIdx.x - NBG;
        const int t = threadIdx.x;
        const int i = blk * 256 + t;
        int v = (i < N) ? hist[i] : 0;
        sm[t] = v;
        __syncthreads();
#pragma unroll
        for (int off = 1; off < 256; off <<= 1) {
            int x = (t >= off) ? sm[t - off] : 0;
            __syncthreads();
            sm[t] += x;
            __syncthreads();
        }
        if (i < N) rofs[i] = sm[t] - v;
        if (t == 255) bsum[blk] = sm[255];
        return;
    }
    // ---- gemm1: h1 = x0 @ W1 (+ fused logits via fold tile) ----
    const int wv = threadIdx.x >> 6;
    const int lane = threadIdx.x & 63;
    const int quad = lane >> 4, c = lane & 15;
    const int base_m = blockIdx.x * 128 + wv * 32;
    bf16x8 af[2][4];
#pragma unroll
    for (int mt = 0; mt < 2; mt++) {
        int row = base_m + mt * 16 + c;
        int rowc = row < N ? row : N - 1;
        const float* ap = x0 + (size_t)rowc * 128 + quad * 8;
#pragma unroll
        for (int ks = 0; ks < 4; ks++) {
            float4 lo = *(const float4*)(ap + ks * 32);
            float4 hi = *(const float4*)(ap + ks * 32 + 4);
            bf16x8 f;
            f[0] = (short)f2b(lo.x); f[1] = (short)f2b(lo.y);
            f[2] = (short)f2b(lo.z); f[3] = (short)f2b(lo.w);
            f[4] = (short)f2b(hi.x); f[5] = (short)f2b(hi.y);
            f[6] = (short)f2b(hi.z); f[7] = (short)f2b(hi.w);
            af[mt][ks] = f;
        }
    }
    for (int nt = 0; nt < 17; nt++) {
        f32x4 acc0 = {0.f, 0.f, 0.f, 0.f};
        f32x4 acc1 = {0.f, 0.f, 0.f, 0.f};
#pragma unroll
        for (int ks = 0; ks < 4; ks++) {
            bf16x8 bf = *(const bf16x8*)(W1T + (size_t)(nt * 16 + c) * 128 + ks * 32 + quad * 8);
            acc0 = __builtin_amdgcn_mfma_f32_16x16x32_bf16(af[0][ks], bf, acc0, 0, 0, 0);
            acc1 = __builtin_amdgcn_mfma_f32_16x16x32_bf16(af[1][ks], bf, acc1, 0, 0, 0);
        }
        if (nt < 16) {
            const int col = nt * 16 + c;
#pragma unroll
            for (int r = 0; r < 4; r++) {
                int row0 = base_m + quad * 4 + r;
                if (row0 < N) h1[(size_t)row0 * 256 + col] = f2q(acc0[r]);
                int row1 = base_m + 16 + quad * 4 + r;
                if (row1 < N) h1[(size_t)row1 * 256 + col] = f2q(acc1[r]);
            }
        } else {
            float* dst = (c < 8) ? a_src : a_dst;
            int hh = c & 7;
#pragma unroll
            for (int r = 0; r < 4; r++) {
                int row0 = base_m + quad * 4 + r;
                if (row0 < N) dst[(size_t)row0 * 8 + hh] = acc0[r];
                int row1 = base_m + 16 + quad * 4 + r;
                if (row1 < N) dst[(size_t)row1 * 8 + hh] = acc1[r];
            }
        }
    }
}

__global__ __launch_bounds__(512) void scan2_kernel(int* __restrict__ bsum) {
    __shared__ int sm[512];
    const int t = threadIdx.x;
    int v = (t < NB1) ? bsum[t] : 0;
    sm[t] = v;
    __syncthreads();
#pragma unroll
    for (int off = 1; off < 512; off <<= 1) {
        int x = (t >= off) ? sm[t - off] : 0;
        __syncthreads();
        sm[t] += x;
        __syncthreads();
    }
    if (t < NB1) bsum[t] = sm[t] - v;
}

__global__ __launch_bounds__(256) void scan3_kernel(int* __restrict__ rofs,
                                                    const int* __restrict__ bsum,
                                                    int* __restrict__ cursor) {
    const int i = blockIdx.x * 256 + threadIdx.x;
    if (i < N) {
        int r = rofs[i] + bsum[blockIdx.x];
        rofs[i] = r;
        cursor[i] = r;
    }
    if (i == 0) rofs[N] = ETOT;
}

// scatter stays SOLO: its cursor/esrc working set must own the L2 (R11 lesson)
__global__ __launch_bounds__(256) void scatter_kernel(const int* __restrict__ ei,
                                                      int* __restrict__ cursor,
                                                      int* __restrict__ esrc) {
    const int e = blockIdx.x * 256 + threadIdx.x;
    if (e >= ETOT) return;
    int s, d;
    if (e < E) { s = ei[e]; d = ei[E + e]; } else { s = d = e - E; }
    int pos = atomicAdd(&cursor[d], 1);
    esrc[pos] = s;
}

// ---------------- layer 1 aggregate v5: wave/node; 1 exp per 8 edges; fp8 h1 gathers (4 B/lane) ----------------
__global__ __launch_bounds__(256) void seg1_kernel(const int* __restrict__ esrc,
                                                   const int* __restrict__ rofs,
                                                   const float* __restrict__ a_src,
                                                   const float* __restrict__ a_dst,
                                                   const unsigned char* __restrict__ h1,
                                                   const float* __restrict__ b1,
                                                   unsigned short* __restrict__ x2) {
    const int n = (blockIdx.x * 256 + threadIdx.x) >> 6;   // wave-uniform node
    const int lane = threadIdx.x & 63;
    const int e_pa = lane >> 3;          // phase-A edge slot 0..7
    const int h_pa = lane & 7;           // phase-A head
    const int hB = lane >> 3;            // phase-B/epilogue head
    const int rs = __builtin_amdgcn_readfirstlane(rofs[n]);
    const int re = __builtin_amdgcn_readfirstlane(rofs[n + 1]);
    const float ad_pa = a_dst[(size_t)n * 8 + h_pa];
    float dsum = 0.f;
    float4 Aa = {0, 0, 0, 0}, Ab = {0, 0, 0, 0};
    for (int j0 = rs; j0 < re; j0 += 8) {
        // phase A: weights for 8 edges x 8 heads, ONE v_exp
        int jm = j0 + e_pa;
        int jc = jm < re ? jm : re - 1;
        int s8 = esrc[jc];
        float av = a_src[(size_t)s8 * 8 + h_pa];
        float ex = __expf(lrelu(av + ad_pa));
        float w = (jm < re) ? ex : 0.f;
        dsum += w;
        // phase B: all 8 gathers issue unconditionally (dead edges clamp to re-1, w=0 masks)
#pragma unroll
        for (int e = 0; e < 8; e++) {
            float wb = __shfl(w, e * 8 + hB, 64);
            int se = __builtin_amdgcn_readlane(s8, e * 8);
            unsigned hv = ((const unsigned*)(h1 + (size_t)se * 256))[lane];
            f32x2 lo = __builtin_amdgcn_cvt_pk_f32_fp8(hv, false);
            f32x2 hi = __builtin_amdgcn_cvt_pk_f32_fp8(hv, true);
            if (e & 1) {
                Ab.x += wb * lo[0]; Ab.y += wb * lo[1];
                Ab.z += wb * hi[0]; Ab.w += wb * hi[1];
            } else {
                Aa.x += wb * lo[0]; Aa.y += wb * lo[1];
                Aa.z += wb * hi[0]; Aa.w += wb * hi[1];
            }
        }
    }
    // reduce dsum over the 8 edge slots
    dsum += __shfl_xor(dsum, 8, 64);
    dsum += __shfl_xor(dsum, 16, 64);
    dsum += __shfl_xor(dsum, 32, 64);
    float den = __shfl(dsum, hB, 64);    // lane L<8 holds den for head L
    float4 acc = {Aa.x + Ab.x, Aa.y + Ab.y, Aa.z + Ab.z, Aa.w + Ab.w};
    const float inv = 1.0f / den;
    float4 bb = ((const float4*)b1)[lane];
    float vx = acc.x * inv + bb.x, vy = acc.y * inv + bb.y;
    float vz = acc.z * inv + bb.z, vw = acc.w * inv + bb.w;
    vx = vx > 0.f ? vx : 0.f; vy = vy > 0.f ? vy : 0.f;
    vz = vz > 0.f ? vz : 0.f; vw = vw > 0.f ? vw : 0.f;
    ushort4 o = {f2b(vx), f2b(vy), f2b(vz), f2b(vw)};
    ((ushort4*)(x2 + (size_t)n * 256))[lane] = o;
}

// ---------------- layer 2 GEMM via MFMA: h2 = x2 @ W2 (256->32), fused logits ----------------
__global__ __launch_bounds__(256) void gemm2_kernel(const unsigned short* __restrict__ x2,
                                                    const unsigned short* __restrict__ W2T,
                                                    const float* __restrict__ att_src2,
                                                    const float* __restrict__ att_dst2,
                                                    unsigned short* __restrict__ h2,
                                                    float* __restrict__ a_src2,
                                                    float* __restrict__ a_dst2) {
    const int wv = threadIdx.x >> 6;
    const int lane = threadIdx.x & 63;
    const int quad = lane >> 4, c = lane & 15;
    const int base_m = blockIdx.x * 128 + wv * 32;
    f32x4 acc[2][2] = {{{0, 0, 0, 0}, {0, 0, 0, 0}}, {{0, 0, 0, 0}, {0, 0, 0, 0}}};
#pragma unroll
    for (int ks = 0; ks < 8; ks++) {
        bf16x8 b0 = *(const bf16x8*)(W2T + (size_t)c * 256 + ks * 32 + quad * 8);
        bf16x8 b1 = *(const bf16x8*)(W2T + (size_t)(16 + c) * 256 + ks * 32 + quad * 8);
#pragma unroll
        for (int mt = 0; mt < 2; mt++) {
            int row = base_m + mt * 16 + c;
            int rowc = row < N ? row : N - 1;
            bf16x8 a = *(const bf16x8*)(x2 + (size_t)rowc * 256 + ks * 32 + quad * 8);
            acc[mt][0] = __builtin_amdgcn_mfma_f32_16x16x32_bf16(a, b0, acc[mt][0], 0, 0, 0);
            acc[mt][1] = __builtin_amdgcn_mfma_f32_16x16x32_bf16(a, b1, acc[mt][1], 0, 0, 0);
        }
    }
    float as0 = att_src2[c], as1 = att_src2[16 + c];
    float ad0 = att_dst2[c], ad1 = att_dst2[16 + c];
#pragma unroll
    for (int mt = 0; mt < 2; mt++) {
#pragma unroll
        for (int r = 0; r < 4; r++) {
            int row = base_m + mt * 16 + quad * 4 + r;
            float v0 = acc[mt][0][r], v1 = acc[mt][1][r];
            float ps = v0 * as0 + v1 * as1;
            float pd = v0 * ad0 + v1 * ad1;
#pragma unroll
            for (int off = 1; off < 16; off <<= 1) {
                ps += __shfl_xor(ps, off, 64);
                pd += __shfl_xor(pd, off, 64);
            }
            if (row < N) {
                h2[(size_t)row * 32 + c] = f2b(v0);
                h2[(size_t)row * 32 + 16 + c] = f2b(v1);
                if (c == 0) { a_src2[row] = ps; a_dst2[row] = pd; }
            }
        }
    }
}

// ---------------- layer 2 aggregate + final linear fused: half-wave/node, masked 8 chains (R9 form) ----------------
__global__ __launch_bounds__(256) void seg2_kernel(const int* __restrict__ esrc,
                                                   const int* __restrict__ rofs,
                                                   const float* __restrict__ a_src2,
                                                   const float* __restrict__ a_dst2,
                                                   const unsigned short* __restrict__ h2,
                                                   const float* __restrict__ b2,
                                                   const float* __restrict__ linW,
                                                   const float* __restrict__ linb,
                                                   float* __restrict__ out) {
    __shared__ float lws[32 * 40];
    __shared__ float vbuf[8][32];
    const int t = threadIdx.x;
    for (int i = t; i < 1280; i += 256) lws[i] = linW[i];
    const int n8 = t >> 5;
    const int c = t & 31;
    const int n = blockIdx.x * 8 + n8;      // N % 8 == 0 -> always valid
    const int rs = rofs[n], re = rofs[n + 1];
    const float ad = a_dst2[n];
    float d[8] = {0, 0, 0, 0, 0, 0, 0, 0};
    float A[8] = {0, 0, 0, 0, 0, 0, 0, 0};
    for (int j0 = rs; j0 < re; j0 += 8) {
        int sidx[8];
#pragma unroll
        for (int k = 0; k < 8; k++) {
            int j = j0 + k;
            sidx[k] = esrc[j < re ? j : re - 1];
        }
        unsigned short hb[8];
        float as[8];
#pragma unroll
        for (int k = 0; k < 8; k++) {
            hb[k] = h2[(size_t)sidx[k] * 32 + c];
            as[k] = a_src2[sidx[k]];
        }
#pragma unroll
        for (int k = 0; k < 8; k++) {
            float w = (j0 + k < re) ? __expf(lrelu(as[k] + ad)) : 0.f;
            d[k] += w;
            A[k] += w * b2f(hb[k]);
        }
    }
    float den = ((d[0] + d[1]) + (d[2] + d[3])) + ((d[4] + d[5]) + (d[6] + d[7]));
    float acc = ((A[0] + A[1]) + (A[2] + A[3])) + ((A[4] + A[5]) + (A[6] + A[7]));
    vbuf[n8][c] = acc / den + b2[c];
    __syncthreads();
    for (int idx = t; idx < 320; idx += 256) {
        int nn = idx / 40, o = idx - nn * 40;
        float s = linb[o];
#pragma unroll
        for (int ci = 0; ci < 32; ci++) s += vbuf[nn][ci] * lws[ci * 40 + o];
        out[(size_t)blockIdx.x * 320 + idx] = s;
    }
}

extern "C" void kernel_launch(void* const* d_in, const int* in_sizes, int n_in,
                              void* d_out, int out_size, void* d_ws, size_t ws_size,
                              hipStream_t stream) {
    const float* x0       = (const float*)d_in[0];
    const float* W1       = (const float*)d_in[1];
    const float* att_src1 = (const float*)d_in[2];
    const float* att_dst1 = (const float*)d_in[3];
    const float* b1       = (const float*)d_in[4];
    const float* W2       = (const float*)d_in[5];
    const float* att_src2 = (const float*)d_in[6];
    const float* att_dst2 = (const float*)d_in[7];
    const float* b2       = (const float*)d_in[8];
    const float* linW     = (const float*)d_in[9];
    const float* linb     = (const float*)d_in[10];
    const int*   ei       = (const int*)d_in[11];
    float* out = (float*)d_out;
    float* ws  = (float*)d_ws;

    unsigned char* h1    = (unsigned char*)ws;                   // 25.6M fp8 = 6.4M floats
    unsigned short* x2   = (unsigned short*)(ws + 6400000);      // 25.6M bf16 = 12.8M floats
    float* a_src1        = ws + 19200000;                        // 0.8M
    float* a_dst1        = ws + 20000000;                        // 0.8M
    unsigned short* h2   = (unsigned short*)(ws + 20800000);     // 3.2M bf16 = 1.6M floats
    float* a_src2        = ws + 22400000;                        // 0.1M
    float* a_dst2        = ws + 22500000;                        // 0.1M
    unsigned short* W1T  = (unsigned short*)(ws + 22600000);     // 272*128 bf16
    unsigned short* W2T  = (unsigned short*)(ws + 22620000);     // 32*256 bf16
    int*   hist          = (int*)(ws + 22630000);                // 0.1M
    int*   rofs          = (int*)(ws + 22730000);                // N+1
    int*   cursor        = (int*)(ws + 22840000);                // 0.1M
    int*   bsum          = (int*)(ws + 22940000);                // 512
    int*   esrc          = (int*)(ws + 22941000);                // 1.1M

    hipMemsetAsync(hist, 0, (size_t)N * 4, stream);

    prep_kernel<<<NBE + 168, 256, 0, stream>>>(ei, hist, W1, W2, att_src1, att_dst1, W1T, W2T);
    // merged gemm1 + scan1 (both depend only on prep; scan1 is atomic-free and tiny)
    g1s_kernel<<<NBG + NB1, 256, 0, stream>>>(x0, W1T, h1, a_src1, a_dst1, hist, rofs, bsum);
    scan2_kernel<<<1, 512, 0, stream>>>(bsum);
    scan3_kernel<<<NB1, 256, 0, stream>>>(rofs, bsum, cursor);
    scatter_kernel<<<(ETOT + 255) / 256, 256, 0, stream>>>(ei, cursor, esrc);

    seg1_kernel<<<N / 4, 256, 0, stream>>>(esrc, rofs, a_src1, a_dst1, h1, b1, x2);
    gemm2_kernel<<<(N + 127) / 128, 256, 0, stream>>>(x2, W2T, att_src2, att_dst2, h2, a_src2, a_dst2);
    seg2_kernel<<<N / 8, 256, 0, stream>>>(esrc, rofs, a_src2, a_dst2, h2, b2, linW, linb, out);
}

// Round 14
// 375.374 us; speedup vs baseline: 1.2199x; 1.0707x over previous
//
#include <hip/hip_runtime.h>

#define N 100000
#define E 1000000
#define ETOT 1100000   // E + N self-loops
#define NB1 391        // ceil(N/256)
#define NBE 4297       // ceil(ETOT/256)
#define NBG 782        // ceil(N/128) gemm1 blocks
#define BUCKET 12500   // N/8 — dst range per XCD bucket

typedef __attribute__((ext_vector_type(8))) short bf16x8;
typedef __attribute__((ext_vector_type(4))) float f32x4;
typedef __attribute__((ext_vector_type(2))) float f32x2;

__device__ __forceinline__ float lrelu(float x) { return x > 0.f ? x : 0.2f * x; }
// f32 -> bf16 bits, round-to-nearest-even
__device__ __forceinline__ unsigned short f2b(float x) {
    unsigned u = __float_as_uint(x);
    return (unsigned short)((u + 0x7FFFu + ((u >> 16) & 1u)) >> 16);
}
__device__ __forceinline__ float b2f(unsigned short v) {
    return __uint_as_float(((unsigned)v) << 16);
}
// f32 -> fp8 e4m3 (OCP), HW round-to-nearest-even
__device__ __forceinline__ unsigned char f2q(float x) {
    return (unsigned char)(__builtin_amdgcn_cvt_pk_fp8_f32(x, x, 0, false) & 0xFF);
}

// ---------------- CSR histogram + weight prep (independent work, one dispatch) ----------------
__global__ __launch_bounds__(256) void prep_kernel(const int* __restrict__ ei,
                                                   int* __restrict__ hist,
                                                   const float* __restrict__ W1,
                                                   const float* __restrict__ W2,
                                                   const float* __restrict__ att_src1,
                                                   const float* __restrict__ att_dst1,
                                                   unsigned short* __restrict__ W1T,
                                                   unsigned short* __restrict__ W2T) {
    const int b = blockIdx.x;
    const int t = threadIdx.x;
    if (b < NBE) {
        const int e = b * 256 + t;
        if (e < ETOT) {
            int d = (e < E) ? ei[E + e] : (e - E);
            atomicAdd(&hist[d], 1);
        }
        return;
    }
    const int bb = b - NBE;
    if (bb < 128) {
        W1T[(size_t)t * 128 + bb] = f2b(W1[(size_t)bb * 256 + t]);
    } else if (bb < 160) {
        int n = bb - 128;
        W2T[(size_t)n * 256 + t] = f2b(W2[(size_t)t * 32 + n]);
    } else {
        int idx = (bb - 160) * 256 + t;         // 0..2047
        int col = idx >> 7;                     // 0..15
        int k = idx & 127;
        int h = col & 7;
        const float* att = (col < 8) ? att_src1 : att_dst1;
        float acc = 0.f;
#pragma unroll 8
        for (int j = 0; j < 32; j++) acc += W1[(size_t)k * 256 + h * 32 + j] * att[h * 32 + j];
        W1T[(size_t)(256 + col) * 128 + k] = f2b(acc);
    }
}

// ---------------- merged: layer-1 GEMM (blocks 0..NBG-1) + scan1 (blocks NBG..) ----------------
// h1 is stored fp8 e4m3 (storage-only quantization; f32 accumulate downstream)
__global__ __launch_bounds__(256) void g1s_kernel(const float* __restrict__ x0,
                                                  const unsigned short* __restrict__ W1T,
                                                  unsigned char* __restrict__ h1,
                                                  float* __restrict__ a_src,
                                                  float* __restrict__ a_dst,
                                                  const int* __restrict__ hist,
                                                  int* __restrict__ rofs,
                                                  int* __restrict__ bsum) {
    __shared__ int sm[256];
    if (blockIdx.x >= NBG) {
        // ---- scan1: block-local exclusive scan of hist ----
        const int blk = blockIdx.x - NBG;
        const int t = threadIdx.x;
        const int i = blk * 256 + t;
        int v = (i < N) ? hist[i] : 0;
        sm[t] = v;
        __syncthreads();
#pragma unroll
        for (int off = 1; off < 256; off <<= 1) {
            int x = (t >= off) ? sm[t - off] : 0;
            __syncthreads();
            sm[t] += x;
            __syncthreads();
        }
        if (i < N) rofs[i] = sm[t] - v;
        if (t == 255) bsum[blk] = sm[255];
        return;
    }
    // ---- gemm1: h1 = x0 @ W1 (+ fused logits via fold tile) ----
    const int wv = threadIdx.x >> 6;
    const int lane = threadIdx.x & 63;
    const int quad = lane >> 4, c = lane & 15;
    const int base_m = blockIdx.x * 128 + wv * 32;
    bf16x8 af[2][4];
#pragma unroll
    for (int mt = 0; mt < 2; mt++) {
        int row = base_m + mt * 16 + c;
        int rowc = row < N ? row : N - 1;
        const float* ap = x0 + (size_t)rowc * 128 + quad * 8;
#pragma unroll
        for (int ks = 0; ks < 4; ks++) {
            float4 lo = *(const float4*)(ap + ks * 32);
            float4 hi = *(const float4*)(ap + ks * 32 + 4);
            bf16x8 f;
            f[0] = (short)f2b(lo.x); f[1] = (short)f2b(lo.y);
            f[2] = (short)f2b(lo.z); f[3] = (short)f2b(lo.w);
            f[4] = (short)f2b(hi.x); f[5] = (short)f2b(hi.y);
            f[6] = (short)f2b(hi.z); f[7] = (short)f2b(hi.w);
            af[mt][ks] = f;
        }
    }
    for (int nt = 0; nt < 17; nt++) {
        f32x4 acc0 = {0.f, 0.f, 0.f, 0.f};
        f32x4 acc1 = {0.f, 0.f, 0.f, 0.f};
#pragma unroll
        for (int ks = 0; ks < 4; ks++) {
            bf16x8 bf = *(const bf16x8*)(W1T + (size_t)(nt * 16 + c) * 128 + ks * 32 + quad * 8);
            acc0 = __builtin_amdgcn_mfma_f32_16x16x32_bf16(af[0][ks], bf, acc0, 0, 0, 0);
            acc1 = __builtin_amdgcn_mfma_f32_16x16x32_bf16(af[1][ks], bf, acc1, 0, 0, 0);
        }
        if (nt < 16) {
            const int col = nt * 16 + c;
#pragma unroll
            for (int r = 0; r < 4; r++) {
                int row0 = base_m + quad * 4 + r;
                if (row0 < N) h1[(size_t)row0 * 256 + col] = f2q(acc0[r]);
                int row1 = base_m + 16 + quad * 4 + r;
                if (row1 < N) h1[(size_t)row1 * 256 + col] = f2q(acc1[r]);
            }
        } else {
            float* dst = (c < 8) ? a_src : a_dst;
            int hh = c & 7;
#pragma unroll
            for (int r = 0; r < 4; r++) {
                int row0 = base_m + quad * 4 + r;
                if (row0 < N) dst[(size_t)row0 * 8 + hh] = acc0[r];
                int row1 = base_m + 16 + quad * 4 + r;
                if (row1 < N) dst[(size_t)row1 * 8 + hh] = acc1[r];
            }
        }
    }
}

__global__ __launch_bounds__(512) void scan2_kernel(int* __restrict__ bsum) {
    __shared__ int sm[512];
    const int t = threadIdx.x;
    int v = (t < NB1) ? bsum[t] : 0;
    sm[t] = v;
    __syncthreads();
#pragma unroll
    for (int off = 1; off < 512; off <<= 1) {
        int x = (t >= off) ? sm[t - off] : 0;
        __syncthreads();
        sm[t] += x;
        __syncthreads();
    }
    if (t < NB1) bsum[t] = sm[t] - v;
}

__global__ __launch_bounds__(256) void scan3_kernel(int* __restrict__ rofs,
                                                    const int* __restrict__ bsum,
                                                    int* __restrict__ cursor) {
    const int i = blockIdx.x * 256 + threadIdx.x;
    if (i < N) {
        int r = rofs[i] + bsum[blockIdx.x];
        rofs[i] = r;
        cursor[i] = r;
    }
    if (i == 0) rofs[N] = ETOT;
}

// ---------------- scatter, XCD-bucketed ----------------
// block b: edge window b>>3, dst bucket b&7. With round-robin blockIdx%8 -> XCD
// dispatch, bucket k's cursor/esrc region is written only from XCD k: lines
// accumulate all ~16 entries in that L2 before one writeback (R13: 16x write
// amplification was the scatter bottleneck). Correct under ANY block->XCD map.
__global__ __launch_bounds__(256) void scatter_kernel(const int* __restrict__ ei,
                                                      int* __restrict__ cursor,
                                                      int* __restrict__ esrc) {
    const int w = blockIdx.x >> 3;
    const int k = blockIdx.x & 7;
    const int e = w * 256 + threadIdx.x;
    if (e >= ETOT) return;
    int s, d;
    if (e < E) { s = ei[e]; d = ei[E + e]; } else { s = d = e - E; }
    if (d / BUCKET != k) return;
    int pos = atomicAdd(&cursor[d], 1);
    esrc[pos] = s;
}

// ---------------- layer 1 aggregate v5: wave/node; 1 exp per 8 edges; fp8 h1 gathers (4 B/lane) ----------------
__global__ __launch_bounds__(256) void seg1_kernel(const int* __restrict__ esrc,
                                                   const int* __restrict__ rofs,
                                                   const float* __restrict__ a_src,
                                                   const float* __restrict__ a_dst,
                                                   const unsigned char* __restrict__ h1,
                                                   const float* __restrict__ b1,
                                                   unsigned short* __restrict__ x2) {
    const int n = (blockIdx.x * 256 + threadIdx.x) >> 6;   // wave-uniform node
    const int lane = threadIdx.x & 63;
    const int e_pa = lane >> 3;          // phase-A edge slot 0..7
    const int h_pa = lane & 7;           // phase-A head
    const int hB = lane >> 3;            // phase-B/epilogue head
    const int rs = __builtin_amdgcn_readfirstlane(rofs[n]);
    const int re = __builtin_amdgcn_readfirstlane(rofs[n + 1]);
    const float ad_pa = a_dst[(size_t)n * 8 + h_pa];
    float dsum = 0.f;
    float4 Aa = {0, 0, 0, 0}, Ab = {0, 0, 0, 0};
    for (int j0 = rs; j0 < re; j0 += 8) {
        // phase A: weights for 8 edges x 8 heads, ONE v_exp
        int jm = j0 + e_pa;
        int jc = jm < re ? jm : re - 1;
        int s8 = esrc[jc];
        float av = a_src[(size_t)s8 * 8 + h_pa];
        float ex = __expf(lrelu(av + ad_pa));
        float w = (jm < re) ? ex : 0.f;
        dsum += w;
        // phase B: all 8 gathers issue unconditionally (dead edges clamp to re-1, w=0 masks)
#pragma unroll
        for (int e = 0; e < 8; e++) {
            float wb = __shfl(w, e * 8 + hB, 64);
            int se = __builtin_amdgcn_readlane(s8, e * 8);
            unsigned hv = ((const unsigned*)(h1 + (size_t)se * 256))[lane];
            f32x2 lo = __builtin_amdgcn_cvt_pk_f32_fp8(hv, false);
            f32x2 hi = __builtin_amdgcn_cvt_pk_f32_fp8(hv, true);
            if (e & 1) {
                Ab.x += wb * lo[0]; Ab.y += wb * lo[1];
                Ab.z += wb * hi[0]; Ab.w += wb * hi[1];
            } else {
                Aa.x += wb * lo[0]; Aa.y += wb * lo[1];
                Aa.z += wb * hi[0]; Aa.w += wb * hi[1];
            }
        }
    }
    // reduce dsum over the 8 edge slots
    dsum += __shfl_xor(dsum, 8, 64);
    dsum += __shfl_xor(dsum, 16, 64);
    dsum += __shfl_xor(dsum, 32, 64);
    float den = __shfl(dsum, hB, 64);    // lane L<8 holds den for head L
    float4 acc = {Aa.x + Ab.x, Aa.y + Ab.y, Aa.z + Ab.z, Aa.w + Ab.w};
    const float inv = 1.0f / den;
    float4 bb = ((const float4*)b1)[lane];
    float vx = acc.x * inv + bb.x, vy = acc.y * inv + bb.y;
    float vz = acc.z * inv + bb.z, vw = acc.w * inv + bb.w;
    vx = vx > 0.f ? vx : 0.f; vy = vy > 0.f ? vy : 0.f;
    vz = vz > 0.f ? vz : 0.f; vw = vw > 0.f ? vw : 0.f;
    ushort4 o = {f2b(vx), f2b(vy), f2b(vz), f2b(vw)};
    ((ushort4*)(x2 + (size_t)n * 256))[lane] = o;
}

// ---------------- layer 2 GEMM via MFMA: h2 = x2 @ W2 (256->32), fused logits ----------------
__global__ __launch_bounds__(256) void gemm2_kernel(const unsigned short* __restrict__ x2,
                                                    const unsigned short* __restrict__ W2T,
                                                    const float* __restrict__ att_src2,
                                                    const float* __restrict__ att_dst2,
                                                    unsigned short* __restrict__ h2,
                                                    float* __restrict__ a_src2,
                                                    float* __restrict__ a_dst2) {
    const int wv = threadIdx.x >> 6;
    const int lane = threadIdx.x & 63;
    const int quad = lane >> 4, c = lane & 15;
    const int base_m = blockIdx.x * 128 + wv * 32;
    f32x4 acc[2][2] = {{{0, 0, 0, 0}, {0, 0, 0, 0}}, {{0, 0, 0, 0}, {0, 0, 0, 0}}};
#pragma unroll
    for (int ks = 0; ks < 8; ks++) {
        bf16x8 b0 = *(const bf16x8*)(W2T + (size_t)c * 256 + ks * 32 + quad * 8);
        bf16x8 b1 = *(const bf16x8*)(W2T + (size_t)(16 + c) * 256 + ks * 32 + quad * 8);
#pragma unroll
        for (int mt = 0; mt < 2; mt++) {
            int row = base_m + mt * 16 + c;
            int rowc = row < N ? row : N - 1;
            bf16x8 a = *(const bf16x8*)(x2 + (size_t)rowc * 256 + ks * 32 + quad * 8);
            acc[mt][0] = __builtin_amdgcn_mfma_f32_16x16x32_bf16(a, b0, acc[mt][0], 0, 0, 0);
            acc[mt][1] = __builtin_amdgcn_mfma_f32_16x16x32_bf16(a, b1, acc[mt][1], 0, 0, 0);
        }
    }
    float as0 = att_src2[c], as1 = att_src2[16 + c];
    float ad0 = att_dst2[c], ad1 = att_dst2[16 + c];
#pragma unroll
    for (int mt = 0; mt < 2; mt++) {
#pragma unroll
        for (int r = 0; r < 4; r++) {
            int row = base_m + mt * 16 + quad * 4 + r;
            float v0 = acc[mt][0][r], v1 = acc[mt][1][r];
            float ps = v0 * as0 + v1 * as1;
            float pd = v0 * ad0 + v1 * ad1;
#pragma unroll
            for (int off = 1; off < 16; off <<= 1) {
                ps += __shfl_xor(ps, off, 64);
                pd += __shfl_xor(pd, off, 64);
            }
            if (row < N) {
                h2[(size_t)row * 32 + c] = f2b(v0);
                h2[(size_t)row * 32 + 16 + c] = f2b(v1);
                if (c == 0) { a_src2[row] = ps; a_dst2[row] = pd; }
            }
        }
    }
}

// ---------------- layer 2 aggregate + final linear fused: half-wave/node, masked 8 chains (R9 form) ----------------
__global__ __launch_bounds__(256) void seg2_kernel(const int* __restrict__ esrc,
                                                   const int* __restrict__ rofs,
                                                   const float* __restrict__ a_src2,
                                                   const float* __restrict__ a_dst2,
                                                   const unsigned short* __restrict__ h2,
                                                   const float* __restrict__ b2,
                                                   const float* __restrict__ linW,
                                                   const float* __restrict__ linb,
                                                   float* __restrict__ out) {
    __shared__ float lws[32 * 40];
    __shared__ float vbuf[8][32];
    const int t = threadIdx.x;
    for (int i = t; i < 1280; i += 256) lws[i] = linW[i];
    const int n8 = t >> 5;
    const int c = t & 31;
    const int n = blockIdx.x * 8 + n8;      // N % 8 == 0 -> always valid
    const int rs = rofs[n], re = rofs[n + 1];
    const float ad = a_dst2[n];
    float d[8] = {0, 0, 0, 0, 0, 0, 0, 0};
    float A[8] = {0, 0, 0, 0, 0, 0, 0, 0};
    for (int j0 = rs; j0 < re; j0 += 8) {
        int sidx[8];
#pragma unroll
        for (int k = 0; k < 8; k++) {
            int j = j0 + k;
            sidx[k] = esrc[j < re ? j : re - 1];
        }
        unsigned short hb[8];
        float as[8];
#pragma unroll
        for (int k = 0; k < 8; k++) {
            hb[k] = h2[(size_t)sidx[k] * 32 + c];
            as[k] = a_src2[sidx[k]];
        }
#pragma unroll
        for (int k = 0; k < 8; k++) {
            float w = (j0 + k < re) ? __expf(lrelu(as[k] + ad)) : 0.f;
            d[k] += w;
            A[k] += w * b2f(hb[k]);
        }
    }
    float den = ((d[0] + d[1]) + (d[2] + d[3])) + ((d[4] + d[5]) + (d[6] + d[7]));
    float acc = ((A[0] + A[1]) + (A[2] + A[3])) + ((A[4] + A[5]) + (A[6] + A[7]));
    vbuf[n8][c] = acc / den + b2[c];
    __syncthreads();
    for (int idx = t; idx < 320; idx += 256) {
        int nn = idx / 40, o = idx - nn * 40;
        float s = linb[o];
#pragma unroll
        for (int ci = 0; ci < 32; ci++) s += vbuf[nn][ci] * lws[ci * 40 + o];
        out[(size_t)blockIdx.x * 320 + idx] = s;
    }
}

extern "C" void kernel_launch(void* const* d_in, const int* in_sizes, int n_in,
                              void* d_out, int out_size, void* d_ws, size_t ws_size,
                              hipStream_t stream) {
    const float* x0       = (const float*)d_in[0];
    const float* W1       = (const float*)d_in[1];
    const float* att_src1 = (const float*)d_in[2];
    const float* att_dst1 = (const float*)d_in[3];
    const float* b1       = (const float*)d_in[4];
    const float* W2       = (const float*)d_in[5];
    const float* att_src2 = (const float*)d_in[6];
    const float* att_dst2 = (const float*)d_in[7];
    const float* b2       = (const float*)d_in[8];
    const float* linW     = (const float*)d_in[9];
    const float* linb     = (const float*)d_in[10];
    const int*   ei       = (const int*)d_in[11];
    float* out = (float*)d_out;
    float* ws  = (float*)d_ws;

    unsigned char* h1    = (unsigned char*)ws;                   // 25.6M fp8 = 6.4M floats
    unsigned short* x2   = (unsigned short*)(ws + 6400000);      // 25.6M bf16 = 12.8M floats
    float* a_src1        = ws + 19200000;                        // 0.8M
    float* a_dst1        = ws + 20000000;                        // 0.8M
    unsigned short* h2   = (unsigned short*)(ws + 20800000);     // 3.2M bf16 = 1.6M floats
    float* a_src2        = ws + 22400000;                        // 0.1M
    float* a_dst2        = ws + 22500000;                        // 0.1M
    unsigned short* W1T  = (unsigned short*)(ws + 22600000);     // 272*128 bf16
    unsigned short* W2T  = (unsigned short*)(ws + 22620000);     // 32*256 bf16
    int*   hist          = (int*)(ws + 22630000);                // 0.1M
    int*   rofs          = (int*)(ws + 22730000);                // N+1
    int*   cursor        = (int*)(ws + 22840000);                // 0.1M
    int*   bsum          = (int*)(ws + 22940000);                // 512
    int*   esrc          = (int*)(ws + 22941000);                // 1.1M

    hipMemsetAsync(hist, 0, (size_t)N * 4, stream);

    prep_kernel<<<NBE + 168, 256, 0, stream>>>(ei, hist, W1, W2, att_src1, att_dst1, W1T, W2T);
    // merged gemm1 + scan1 (both depend only on prep; scan1 is atomic-free and tiny)
    g1s_kernel<<<NBG + NB1, 256, 0, stream>>>(x0, W1T, h1, a_src1, a_dst1, hist, rofs, bsum);
    scan2_kernel<<<1, 512, 0, stream>>>(bsum);
    scan3_kernel<<<NB1, 256, 0, stream>>>(rofs, bsum, cursor);
    // XCD-bucketed scatter: 8 blocks per edge window, bucket = blockIdx & 7
    scatter_kernel<<<NBE * 8, 256, 0, stream>>>(ei, cursor, esrc);

    seg1_kernel<<<N / 4, 256, 0, stream>>>(esrc, rofs, a_src1, a_dst1, h1, b1, x2);
    gemm2_kernel<<<(N + 127) / 128, 256, 0, stream>>>(x2, W2T, att_src2, att_dst2, h2, a_src2, a_dst2);
    seg2_kernel<<<N / 8, 256, 0, stream>>>(esrc, rofs, a_src2, a_dst2, h2, b2, linW, linb, out);
}

// Round 15
// 363.923 us; speedup vs baseline: 1.2583x; 1.0315x over previous
//
#include <hip/hip_runtime.h>

#define N 100000
#define E 1000000
#define ETOT 1100000   // E + N self-loops
#define NB1 391        // ceil(N/256)
#define NBE 4297       // ceil(ETOT/256)
#define NBG 782        // ceil(N/128) gemm1 blocks
#define BUCKET 12500   // N/8 — dst range per XCD bucket

typedef __attribute__((ext_vector_type(8))) short bf16x8;
typedef __attribute__((ext_vector_type(4))) float f32x4;
typedef __attribute__((ext_vector_type(2))) float f32x2;

__device__ __forceinline__ float lrelu(float x) { return x > 0.f ? x : 0.2f * x; }
// f32 -> bf16 bits, round-to-nearest-even
__device__ __forceinline__ unsigned short f2b(float x) {
    unsigned u = __float_as_uint(x);
    return (unsigned short)((u + 0x7FFFu + ((u >> 16) & 1u)) >> 16);
}
__device__ __forceinline__ float b2f(unsigned short v) {
    return __uint_as_float(((unsigned)v) << 16);
}
// f32 -> fp8 e4m3 (OCP), HW round-to-nearest-even
__device__ __forceinline__ unsigned char f2q(float x) {
    return (unsigned char)(__builtin_amdgcn_cvt_pk_fp8_f32(x, x, 0, false) & 0xFF);
}

// ---------------- CSR histogram + weight prep (independent work, one dispatch) ----------------
__global__ __launch_bounds__(256) void prep_kernel(const int* __restrict__ ei,
                                                   int* __restrict__ hist,
                                                   const float* __restrict__ W1,
                                                   const float* __restrict__ W2,
                                                   const float* __restrict__ att_src1,
                                                   const float* __restrict__ att_dst1,
                                                   unsigned short* __restrict__ W1T,
                                                   unsigned short* __restrict__ W2T) {
    const int b = blockIdx.x;
    const int t = threadIdx.x;
    if (b < NBE) {
        const int e = b * 256 + t;
        if (e < ETOT) {
            int d = (e < E) ? ei[E + e] : (e - E);
            atomicAdd(&hist[d], 1);
        }
        return;
    }
    const int bb = b - NBE;
    if (bb < 128) {
        W1T[(size_t)t * 128 + bb] = f2b(W1[(size_t)bb * 256 + t]);
    } else if (bb < 160) {
        int n = bb - 128;
        W2T[(size_t)n * 256 + t] = f2b(W2[(size_t)t * 32 + n]);
    } else {
        int idx = (bb - 160) * 256 + t;         // 0..2047
        int col = idx >> 7;                     // 0..15
        int k = idx & 127;
        int h = col & 7;
        const float* att = (col < 8) ? att_src1 : att_dst1;
        float acc = 0.f;
#pragma unroll 8
        for (int j = 0; j < 32; j++) acc += W1[(size_t)k * 256 + h * 32 + j] * att[h * 32 + j];
        W1T[(size_t)(256 + col) * 128 + k] = f2b(acc);
    }
}

// ---------------- merged: layer-1 GEMM (blocks 0..NBG-1) + scan1 (blocks NBG..) ----------------
// h1 is stored fp8 e4m3 (storage-only quantization; f32 accumulate downstream)
__global__ __launch_bounds__(256) void g1s_kernel(const float* __restrict__ x0,
                                                  const unsigned short* __restrict__ W1T,
                                                  unsigned char* __restrict__ h1,
                                                  float* __restrict__ a_src,
                                                  float* __restrict__ a_dst,
                                                  const int* __restrict__ hist,
                                                  int* __restrict__ rofs,
                                                  int* __restrict__ bsum) {
    __shared__ int sm[256];
    if (blockIdx.x >= NBG) {
        // ---- scan1: block-local exclusive scan of hist ----
        const int blk = blockIdx.x - NBG;
        const int t = threadIdx.x;
        const int i = blk * 256 + t;
        int v = (i < N) ? hist[i] : 0;
        sm[t] = v;
        __syncthreads();
#pragma unroll
        for (int off = 1; off < 256; off <<= 1) {
            int x = (t >= off) ? sm[t - off] : 0;
            __syncthreads();
            sm[t] += x;
            __syncthreads();
        }
        if (i < N) rofs[i] = sm[t] - v;
        if (t == 255) bsum[blk] = sm[255];
        return;
    }
    // ---- gemm1: h1 = x0 @ W1 (+ fused logits via fold tile) ----
    const int wv = threadIdx.x >> 6;
    const int lane = threadIdx.x & 63;
    const int quad = lane >> 4, c = lane & 15;
    const int base_m = blockIdx.x * 128 + wv * 32;
    bf16x8 af[2][4];
#pragma unroll
    for (int mt = 0; mt < 2; mt++) {
        int row = base_m + mt * 16 + c;
        int rowc = row < N ? row : N - 1;
        const float* ap = x0 + (size_t)rowc * 128 + quad * 8;
#pragma unroll
        for (int ks = 0; ks < 4; ks++) {
            float4 lo = *(const float4*)(ap + ks * 32);
            float4 hi = *(const float4*)(ap + ks * 32 + 4);
            bf16x8 f;
            f[0] = (short)f2b(lo.x); f[1] = (short)f2b(lo.y);
            f[2] = (short)f2b(lo.z); f[3] = (short)f2b(lo.w);
            f[4] = (short)f2b(hi.x); f[5] = (short)f2b(hi.y);
            f[6] = (short)f2b(hi.z); f[7] = (short)f2b(hi.w);
            af[mt][ks] = f;
        }
    }
    for (int nt = 0; nt < 17; nt++) {
        f32x4 acc0 = {0.f, 0.f, 0.f, 0.f};
        f32x4 acc1 = {0.f, 0.f, 0.f, 0.f};
#pragma unroll
        for (int ks = 0; ks < 4; ks++) {
            bf16x8 bf = *(const bf16x8*)(W1T + (size_t)(nt * 16 + c) * 128 + ks * 32 + quad * 8);
            acc0 = __builtin_amdgcn_mfma_f32_16x16x32_bf16(af[0][ks], bf, acc0, 0, 0, 0);
            acc1 = __builtin_amdgcn_mfma_f32_16x16x32_bf16(af[1][ks], bf, acc1, 0, 0, 0);
        }
        if (nt < 16) {
            const int col = nt * 16 + c;
#pragma unroll
            for (int r = 0; r < 4; r++) {
                int row0 = base_m + quad * 4 + r;
                if (row0 < N) h1[(size_t)row0 * 256 + col] = f2q(acc0[r]);
                int row1 = base_m + 16 + quad * 4 + r;
                if (row1 < N) h1[(size_t)row1 * 256 + col] = f2q(acc1[r]);
            }
        } else {
            float* dst = (c < 8) ? a_src : a_dst;
            int hh = c & 7;
#pragma unroll
            for (int r = 0; r < 4; r++) {
                int row0 = base_m + quad * 4 + r;
                if (row0 < N) dst[(size_t)row0 * 8 + hh] = acc0[r];
                int row1 = base_m + 16 + quad * 4 + r;
                if (row1 < N) dst[(size_t)row1 * 8 + hh] = acc1[r];
            }
        }
    }
}

__global__ __launch_bounds__(512) void scan2_kernel(int* __restrict__ bsum) {
    __shared__ int sm[512];
    const int t = threadIdx.x;
    int v = (t < NB1) ? bsum[t] : 0;
    sm[t] = v;
    __syncthreads();
#pragma unroll
    for (int off = 1; off < 512; off <<= 1) {
        int x = (t >= off) ? sm[t - off] : 0;
        __syncthreads();
        sm[t] += x;
        __syncthreads();
    }
    if (t < NB1) bsum[t] = sm[t] - v;
}

__global__ __launch_bounds__(256) void scan3_kernel(int* __restrict__ rofs,
                                                    const int* __restrict__ bsum,
                                                    int* __restrict__ cursor) {
    const int i = blockIdx.x * 256 + threadIdx.x;
    if (i < N) {
        int r = rofs[i] + bsum[blockIdx.x];
        rofs[i] = r;
        cursor[i] = r;
    }
    if (i == 0) rofs[N] = ETOT;
}

// ---------------- scatter, XCD-bucketed (R14 win: kills 16x write amplification) ----------------
__global__ __launch_bounds__(256) void scatter_kernel(const int* __restrict__ ei,
                                                      int* __restrict__ cursor,
                                                      int* __restrict__ esrc) {
    const int w = blockIdx.x >> 3;
    const int k = blockIdx.x & 7;
    const int e = w * 256 + threadIdx.x;
    if (e >= ETOT) return;
    int s, d;
    if (e < E) { s = ei[e]; d = ei[E + e]; } else { s = d = e - E; }
    if (d / BUCKET != k) return;
    int pos = atomicAdd(&cursor[d], 1);
    esrc[pos] = s;
}

// ---------------- layer 1 aggregate v5: wave/node; 1 exp per 8 edges; fp8 h1 gathers (4 B/lane) ----------------
__global__ __launch_bounds__(256) void seg1_kernel(const int* __restrict__ esrc,
                                                   const int* __restrict__ rofs,
                                                   const float* __restrict__ a_src,
                                                   const float* __restrict__ a_dst,
                                                   const unsigned char* __restrict__ h1,
                                                   const float* __restrict__ b1,
                                                   unsigned short* __restrict__ x2) {
    const int n = (blockIdx.x * 256 + threadIdx.x) >> 6;   // wave-uniform node
    const int lane = threadIdx.x & 63;
    const int e_pa = lane >> 3;          // phase-A edge slot 0..7
    const int h_pa = lane & 7;           // phase-A head
    const int hB = lane >> 3;            // phase-B/epilogue head
    const int rs = __builtin_amdgcn_readfirstlane(rofs[n]);
    const int re = __builtin_amdgcn_readfirstlane(rofs[n + 1]);
    const float ad_pa = a_dst[(size_t)n * 8 + h_pa];
    float dsum = 0.f;
    float4 Aa = {0, 0, 0, 0}, Ab = {0, 0, 0, 0};
    for (int j0 = rs; j0 < re; j0 += 8) {
        // phase A: weights for 8 edges x 8 heads, ONE v_exp
        int jm = j0 + e_pa;
        int jc = jm < re ? jm : re - 1;
        int s8 = esrc[jc];
        float av = a_src[(size_t)s8 * 8 + h_pa];
        float ex = __expf(lrelu(av + ad_pa));
        float w = (jm < re) ? ex : 0.f;
        dsum += w;
        // phase B: all 8 gathers issue unconditionally (dead edges clamp to re-1, w=0 masks)
#pragma unroll
        for (int e = 0; e < 8; e++) {
            float wb = __shfl(w, e * 8 + hB, 64);
            int se = __builtin_amdgcn_readlane(s8, e * 8);
            unsigned hv = ((const unsigned*)(h1 + (size_t)se * 256))[lane];
            f32x2 lo = __builtin_amdgcn_cvt_pk_f32_fp8(hv, false);
            f32x2 hi = __builtin_amdgcn_cvt_pk_f32_fp8(hv, true);
            if (e & 1) {
                Ab.x += wb * lo[0]; Ab.y += wb * lo[1];
                Ab.z += wb * hi[0]; Ab.w += wb * hi[1];
            } else {
                Aa.x += wb * lo[0]; Aa.y += wb * lo[1];
                Aa.z += wb * hi[0]; Aa.w += wb * hi[1];
            }
        }
    }
    // reduce dsum over the 8 edge slots
    dsum += __shfl_xor(dsum, 8, 64);
    dsum += __shfl_xor(dsum, 16, 64);
    dsum += __shfl_xor(dsum, 32, 64);
    float den = __shfl(dsum, hB, 64);    // lane L<8 holds den for head L
    float4 acc = {Aa.x + Ab.x, Aa.y + Ab.y, Aa.z + Ab.z, Aa.w + Ab.w};
    const float inv = 1.0f / den;
    float4 bb = ((const float4*)b1)[lane];
    float vx = acc.x * inv + bb.x, vy = acc.y * inv + bb.y;
    float vz = acc.z * inv + bb.z, vw = acc.w * inv + bb.w;
    vx = vx > 0.f ? vx : 0.f; vy = vy > 0.f ? vy : 0.f;
    vz = vz > 0.f ? vz : 0.f; vw = vw > 0.f ? vw : 0.f;
    ushort4 o = {f2b(vx), f2b(vy), f2b(vz), f2b(vw)};
    ((ushort4*)(x2 + (size_t)n * 256))[lane] = o;
}

// ---------------- layer 2 GEMM via MFMA: h2 = x2 @ W2 (256->32), fused logits ----------------
__global__ __launch_bounds__(256) void gemm2_kernel(const unsigned short* __restrict__ x2,
                                                    const unsigned short* __restrict__ W2T,
                                                    const float* __restrict__ att_src2,
                                                    const float* __restrict__ att_dst2,
                                                    unsigned short* __restrict__ h2,
                                                    float* __restrict__ a_src2,
                                                    float* __restrict__ a_dst2) {
    const int wv = threadIdx.x >> 6;
    const int lane = threadIdx.x & 63;
    const int quad = lane >> 4, c = lane & 15;
    const int base_m = blockIdx.x * 128 + wv * 32;
    f32x4 acc[2][2] = {{{0, 0, 0, 0}, {0, 0, 0, 0}}, {{0, 0, 0, 0}, {0, 0, 0, 0}}};
#pragma unroll
    for (int ks = 0; ks < 8; ks++) {
        bf16x8 b0 = *(const bf16x8*)(W2T + (size_t)c * 256 + ks * 32 + quad * 8);
        bf16x8 b1 = *(const bf16x8*)(W2T + (size_t)(16 + c) * 256 + ks * 32 + quad * 8);
#pragma unroll
        for (int mt = 0; mt < 2; mt++) {
            int row = base_m + mt * 16 + c;
            int rowc = row < N ? row : N - 1;
            bf16x8 a = *(const bf16x8*)(x2 + (size_t)rowc * 256 + ks * 32 + quad * 8);
            acc[mt][0] = __builtin_amdgcn_mfma_f32_16x16x32_bf16(a, b0, acc[mt][0], 0, 0, 0);
            acc[mt][1] = __builtin_amdgcn_mfma_f32_16x16x32_bf16(a, b1, acc[mt][1], 0, 0, 0);
        }
    }
    float as0 = att_src2[c], as1 = att_src2[16 + c];
    float ad0 = att_dst2[c], ad1 = att_dst2[16 + c];
#pragma unroll
    for (int mt = 0; mt < 2; mt++) {
#pragma unroll
        for (int r = 0; r < 4; r++) {
            int row = base_m + mt * 16 + quad * 4 + r;
            float v0 = acc[mt][0][r], v1 = acc[mt][1][r];
            float ps = v0 * as0 + v1 * as1;
            float pd = v0 * ad0 + v1 * ad1;
#pragma unroll
            for (int off = 1; off < 16; off <<= 1) {
                ps += __shfl_xor(ps, off, 64);
                pd += __shfl_xor(pd, off, 64);
            }
            if (row < N) {
                h2[(size_t)row * 32 + c] = f2b(v0);
                h2[(size_t)row * 32 + 16 + c] = f2b(v1);
                if (c == 0) { a_src2[row] = ps; a_dst2[row] = pd; }
            }
        }
    }
}

// ---------------- layer 2 aggregate v4 + fused final: half-wave/node, 8 chains,
// exp deduplicated (lane l computes edge l&7 only; shfl broadcast) ----------------
__global__ __launch_bounds__(256) void seg2_kernel(const int* __restrict__ esrc,
                                                   const int* __restrict__ rofs,
                                                   const float* __restrict__ a_src2,
                                                   const float* __restrict__ a_dst2,
                                                   const unsigned short* __restrict__ h2,
                                                   const float* __restrict__ b2,
                                                   const float* __restrict__ linW,
                                                   const float* __restrict__ linb,
                                                   float* __restrict__ out) {
    __shared__ float lws[32 * 41];   // stride 41 breaks the 40-stride bank pattern
    __shared__ float vbuf[8][33];
    const int t = threadIdx.x;
    for (int i = t; i < 1280; i += 256) {
        int ci = i / 40, o = i - ci * 40;
        lws[ci * 41 + o] = linW[i];
    }
    const int n8 = t >> 5;
    const int c = t & 31;
    const int myk = t & 7;          // the one edge slot this lane computes exp for
    const int n = blockIdx.x * 8 + n8;      // N % 8 == 0 -> always valid
    const int rs = rofs[n], re = rofs[n + 1];
    const float ad = a_dst2[n];
    float dsum = 0.f;
    float A[8] = {0, 0, 0, 0, 0, 0, 0, 0};
    for (int j0 = rs; j0 < re; j0 += 8) {
        int sidx[8];
#pragma unroll
        for (int k = 0; k < 8; k++) {
            int j = j0 + k;
            sidx[k] = esrc[j < re ? j : re - 1];
        }
        // ONE exp per lane (edge myk); 4x dedup vs all-lanes-all-edges
        float av = a_src2[sidx[myk]];
        float myw = (j0 + myk < re) ? __expf(lrelu(av + ad)) : 0.f;
        dsum += myw;
        unsigned short hb[8];
#pragma unroll
        for (int k = 0; k < 8; k++) hb[k] = h2[(size_t)sidx[k] * 32 + c];
#pragma unroll
        for (int k = 0; k < 8; k++) {
            float w = __shfl(myw, (t & 32) + k, 64);   // broadcast within half-wave
            A[k] += w * b2f(hb[k]);
        }
    }
    // den = sum over the 8 myk groups (lanes l, l^1, l^2, l^4 span all k)
    dsum += __shfl_xor(dsum, 1, 64);
    dsum += __shfl_xor(dsum, 2, 64);
    dsum += __shfl_xor(dsum, 4, 64);
    float acc = ((A[0] + A[1]) + (A[2] + A[3])) + ((A[4] + A[5]) + (A[6] + A[7]));
    vbuf[n8][c] = acc / dsum + b2[c];
    __syncthreads();
    for (int idx = t; idx < 320; idx += 256) {
        int nn = idx / 40, o = idx - nn * 40;
        float s = linb[o];
#pragma unroll
        for (int ci = 0; ci < 32; ci++) s += vbuf[nn][ci] * lws[ci * 41 + o];
        out[(size_t)blockIdx.x * 320 + idx] = s;
    }
}

extern "C" void kernel_launch(void* const* d_in, const int* in_sizes, int n_in,
                              void* d_out, int out_size, void* d_ws, size_t ws_size,
                              hipStream_t stream) {
    const float* x0       = (const float*)d_in[0];
    const float* W1       = (const float*)d_in[1];
    const float* att_src1 = (const float*)d_in[2];
    const float* att_dst1 = (const float*)d_in[3];
    const float* b1       = (const float*)d_in[4];
    const float* W2       = (const float*)d_in[5];
    const float* att_src2 = (const float*)d_in[6];
    const float* att_dst2 = (const float*)d_in[7];
    const float* b2       = (const float*)d_in[8];
    const float* linW     = (const float*)d_in[9];
    const float* linb     = (const float*)d_in[10];
    const int*   ei       = (const int*)d_in[11];
    float* out = (float*)d_out;
    float* ws  = (float*)d_ws;

    unsigned char* h1    = (unsigned char*)ws;                   // 25.6M fp8 = 6.4M floats
    unsigned short* x2   = (unsigned short*)(ws + 6400000);      // 25.6M bf16 = 12.8M floats
    float* a_src1        = ws + 19200000;                        // 0.8M
    float* a_dst1        = ws + 20000000;                        // 0.8M
    unsigned short* h2   = (unsigned short*)(ws + 20800000);     // 3.2M bf16 = 1.6M floats
    float* a_src2        = ws + 22400000;                        // 0.1M
    float* a_dst2        = ws + 22500000;                        // 0.1M
    unsigned short* W1T  = (unsigned short*)(ws + 22600000);     // 272*128 bf16
    unsigned short* W2T  = (unsigned short*)(ws + 22620000);     // 32*256 bf16
    int*   hist          = (int*)(ws + 22630000);                // 0.1M
    int*   rofs          = (int*)(ws + 22730000);                // N+1
    int*   cursor        = (int*)(ws + 22840000);                // 0.1M
    int*   bsum          = (int*)(ws + 22940000);                // 512
    int*   esrc          = (int*)(ws + 22941000);                // 1.1M

    hipMemsetAsync(hist, 0, (size_t)N * 4, stream);

    prep_kernel<<<NBE + 168, 256, 0, stream>>>(ei, hist, W1, W2, att_src1, att_dst1, W1T, W2T);
    // merged gemm1 + scan1 (both depend only on prep; scan1 is atomic-free and tiny)
    g1s_kernel<<<NBG + NB1, 256, 0, stream>>>(x0, W1T, h1, a_src1, a_dst1, hist, rofs, bsum);
    scan2_kernel<<<1, 512, 0, stream>>>(bsum);
    scan3_kernel<<<NB1, 256, 0, stream>>>(rofs, bsum, cursor);
    // XCD-bucketed scatter: 8 blocks per edge window, bucket = blockIdx & 7
    scatter_kernel<<<NBE * 8, 256, 0, stream>>>(ei, cursor, esrc);

    seg1_kernel<<<N / 4, 256, 0, stream>>>(esrc, rofs, a_src1, a_dst1, h1, b1, x2);
    gemm2_kernel<<<(N + 127) / 128, 256, 0, stream>>>(x2, W2T, att_src2, att_dst2, h2, a_src2, a_dst2);
    seg2_kernel<<<N / 8, 256, 0, stream>>>(esrc, rofs, a_src2, a_dst2, h2, b2, linW, linb, out);
}

// Round 16
// 363.435 us; speedup vs baseline: 1.2600x; 1.0013x over previous
//
#include <hip/hip_runtime.h>

#define N 100000
#define E 1000000
#define ETOT 1100000   // E + N self-loops
#define NB1 391        // ceil(N/256)
#define NBE 4297       // ceil(ETOT/256)
#define NBH (NBE * 8)  // bucketed-hist blocks
#define NBG 782        // ceil(N/128) gemm1 blocks
#define BUCKET 12500   // N/8 — dst range per XCD bucket

typedef __attribute__((ext_vector_type(8))) short bf16x8;
typedef __attribute__((ext_vector_type(4))) float f32x4;
typedef __attribute__((ext_vector_type(2))) float f32x2;

__device__ __forceinline__ float lrelu(float x) { return x > 0.f ? x : 0.2f * x; }
// f32 -> bf16 bits, round-to-nearest-even
__device__ __forceinline__ unsigned short f2b(float x) {
    unsigned u = __float_as_uint(x);
    return (unsigned short)((u + 0x7FFFu + ((u >> 16) & 1u)) >> 16);
}
__device__ __forceinline__ float b2f(unsigned short v) {
    return __uint_as_float(((unsigned)v) << 16);
}
// f32 -> fp8 e4m3 (OCP), HW round-to-nearest-even
__device__ __forceinline__ unsigned char f2q(float x) {
    return (unsigned char)(__builtin_amdgcn_cvt_pk_fp8_f32(x, x, 0, false) & 0xFF);
}

// ---------------- CSR histogram (XCD-bucketed, R14 transform) + weight prep ----------------
// blocks 0..NBH-1: hist — block b handles edge window b>>3, dst bucket b&7.
// With round-robin blockIdx%8 -> XCD, hist bucket k (50 KB) is atomically
// updated only from XCD k: no cross-XCD line bouncing / writeback amplification.
__global__ __launch_bounds__(256) void prep_kernel(const int* __restrict__ ei,
                                                   int* __restrict__ hist,
                                                   const float* __restrict__ W1,
                                                   const float* __restrict__ W2,
                                                   const float* __restrict__ att_src1,
                                                   const float* __restrict__ att_dst1,
                                                   unsigned short* __restrict__ W1T,
                                                   unsigned short* __restrict__ W2T) {
    const int b = blockIdx.x;
    const int t = threadIdx.x;
    if (b < NBH) {
        const int w = b >> 3;
        const int k = b & 7;
        const int e = w * 256 + t;
        if (e < ETOT) {
            int d = (e < E) ? ei[E + e] : (e - E);
            if (d / BUCKET == k) atomicAdd(&hist[d], 1);
        }
        return;
    }
    const int bb = b - NBH;
    if (bb < 128) {
        W1T[(size_t)t * 128 + bb] = f2b(W1[(size_t)bb * 256 + t]);
    } else if (bb < 160) {
        int n = bb - 128;
        W2T[(size_t)n * 256 + t] = f2b(W2[(size_t)t * 32 + n]);
    } else {
        int idx = (bb - 160) * 256 + t;         // 0..2047
        int col = idx >> 7;                     // 0..15
        int k = idx & 127;
        int h = col & 7;
        const float* att = (col < 8) ? att_src1 : att_dst1;
        float acc = 0.f;
#pragma unroll 8
        for (int j = 0; j < 32; j++) acc += W1[(size_t)k * 256 + h * 32 + j] * att[h * 32 + j];
        W1T[(size_t)(256 + col) * 128 + k] = f2b(acc);
    }
}

// ---------------- merged: layer-1 GEMM (blocks 0..NBG-1) + scan1 (blocks NBG..) ----------------
// h1 is stored fp8 e4m3 (storage-only quantization; f32 accumulate downstream)
__global__ __launch_bounds__(256) void g1s_kernel(const float* __restrict__ x0,
                                                  const unsigned short* __restrict__ W1T,
                                                  unsigned char* __restrict__ h1,
                                                  float* __restrict__ a_src,
                                                  float* __restrict__ a_dst,
                                                  const int* __restrict__ hist,
                                                  int* __restrict__ rofs,
                                                  int* __restrict__ bsum) {
    __shared__ int sm[256];
    if (blockIdx.x >= NBG) {
        // ---- scan1: block-local exclusive scan of hist ----
        const int blk = blockIdx.x - NBG;
        const int t = threadIdx.x;
        const int i = blk * 256 + t;
        int v = (i < N) ? hist[i] : 0;
        sm[t] = v;
        __syncthreads();
#pragma unroll
        for (int off = 1; off < 256; off <<= 1) {
            int x = (t >= off) ? sm[t - off] : 0;
            __syncthreads();
            sm[t] += x;
            __syncthreads();
        }
        if (i < N) rofs[i] = sm[t] - v;
        if (t == 255) bsum[blk] = sm[255];
        return;
    }
    // ---- gemm1: h1 = x0 @ W1 (+ fused logits via fold tile) ----
    const int wv = threadIdx.x >> 6;
    const int lane = threadIdx.x & 63;
    const int quad = lane >> 4, c = lane & 15;
    const int base_m = blockIdx.x * 128 + wv * 32;
    bf16x8 af[2][4];
#pragma unroll
    for (int mt = 0; mt < 2; mt++) {
        int row = base_m + mt * 16 + c;
        int rowc = row < N ? row : N - 1;
        const float* ap = x0 + (size_t)rowc * 128 + quad * 8;
#pragma unroll
        for (int ks = 0; ks < 4; ks++) {
            float4 lo = *(const float4*)(ap + ks * 32);
            float4 hi = *(const float4*)(ap + ks * 32 + 4);
            bf16x8 f;
            f[0] = (short)f2b(lo.x); f[1] = (short)f2b(lo.y);
            f[2] = (short)f2b(lo.z); f[3] = (short)f2b(lo.w);
            f[4] = (short)f2b(hi.x); f[5] = (short)f2b(hi.y);
            f[6] = (short)f2b(hi.z); f[7] = (short)f2b(hi.w);
            af[mt][ks] = f;
        }
    }
    for (int nt = 0; nt < 17; nt++) {
        f32x4 acc0 = {0.f, 0.f, 0.f, 0.f};
        f32x4 acc1 = {0.f, 0.f, 0.f, 0.f};
#pragma unroll
        for (int ks = 0; ks < 4; ks++) {
            bf16x8 bf = *(const bf16x8*)(W1T + (size_t)(nt * 16 + c) * 128 + ks * 32 + quad * 8);
            acc0 = __builtin_amdgcn_mfma_f32_16x16x32_bf16(af[0][ks], bf, acc0, 0, 0, 0);
            acc1 = __builtin_amdgcn_mfma_f32_16x16x32_bf16(af[1][ks], bf, acc1, 0, 0, 0);
        }
        if (nt < 16) {
            const int col = nt * 16 + c;
#pragma unroll
            for (int r = 0; r < 4; r++) {
                int row0 = base_m + quad * 4 + r;
                if (row0 < N) h1[(size_t)row0 * 256 + col] = f2q(acc0[r]);
                int row1 = base_m + 16 + quad * 4 + r;
                if (row1 < N) h1[(size_t)row1 * 256 + col] = f2q(acc1[r]);
            }
        } else {
            float* dst = (c < 8) ? a_src : a_dst;
            int hh = c & 7;
#pragma unroll
            for (int r = 0; r < 4; r++) {
                int row0 = base_m + quad * 4 + r;
                if (row0 < N) dst[(size_t)row0 * 8 + hh] = acc0[r];
                int row1 = base_m + 16 + quad * 4 + r;
                if (row1 < N) dst[(size_t)row1 * 8 + hh] = acc1[r];
            }
        }
    }
}

// ---------------- merged scan2+scan3: each block redundantly reduces the bsum prefix ----------------
__global__ __launch_bounds__(256) void scan23_kernel(int* __restrict__ rofs,
                                                     const int* __restrict__ bsum,
                                                     int* __restrict__ cursor) {
    __shared__ int red[4];
    const int blk = blockIdx.x;
    const int t = threadIdx.x;
    // prefix = sum of bsum[0..blk-1], computed by all 256 threads cooperatively
    int v = 0;
    for (int j = t; j < blk; j += 256) v += bsum[j];
#pragma unroll
    for (int off = 1; off < 64; off <<= 1) v += __shfl_xor(v, off, 64);
    if ((t & 63) == 0) red[t >> 6] = v;
    __syncthreads();
    const int prefix = (red[0] + red[1]) + (red[2] + red[3]);
    const int i = blk * 256 + t;
    if (i < N) {
        int r = rofs[i] + prefix;
        rofs[i] = r;
        cursor[i] = r;
    }
    if (i == 0) rofs[N] = ETOT;
}

// ---------------- scatter, XCD-bucketed (R14 win: kills 16x write amplification) ----------------
__global__ __launch_bounds__(256) void scatter_kernel(const int* __restrict__ ei,
                                                      int* __restrict__ cursor,
                                                      int* __restrict__ esrc) {
    const int w = blockIdx.x >> 3;
    const int k = blockIdx.x & 7;
    const int e = w * 256 + threadIdx.x;
    if (e >= ETOT) return;
    int s, d;
    if (e < E) { s = ei[e]; d = ei[E + e]; } else { s = d = e - E; }
    if (d / BUCKET != k) return;
    int pos = atomicAdd(&cursor[d], 1);
    esrc[pos] = s;
}

// ---------------- layer 1 aggregate v5: wave/node; 1 exp per 8 edges; fp8 h1 gathers (4 B/lane) ----------------
__global__ __launch_bounds__(256) void seg1_kernel(const int* __restrict__ esrc,
                                                   const int* __restrict__ rofs,
                                                   const float* __restrict__ a_src,
                                                   const float* __restrict__ a_dst,
                                                   const unsigned char* __restrict__ h1,
                                                   const float* __restrict__ b1,
                                                   unsigned short* __restrict__ x2) {
    const int n = (blockIdx.x * 256 + threadIdx.x) >> 6;   // wave-uniform node
    const int lane = threadIdx.x & 63;
    const int e_pa = lane >> 3;          // phase-A edge slot 0..7
    const int h_pa = lane & 7;           // phase-A head
    const int hB = lane >> 3;            // phase-B/epilogue head
    const int rs = __builtin_amdgcn_readfirstlane(rofs[n]);
    const int re = __builtin_amdgcn_readfirstlane(rofs[n + 1]);
    const float ad_pa = a_dst[(size_t)n * 8 + h_pa];
    float dsum = 0.f;
    float4 Aa = {0, 0, 0, 0}, Ab = {0, 0, 0, 0};
    for (int j0 = rs; j0 < re; j0 += 8) {
        // phase A: weights for 8 edges x 8 heads, ONE v_exp
        int jm = j0 + e_pa;
        int jc = jm < re ? jm : re - 1;
        int s8 = esrc[jc];
        float av = a_src[(size_t)s8 * 8 + h_pa];
        float ex = __expf(lrelu(av + ad_pa));
        float w = (jm < re) ? ex : 0.f;
        dsum += w;
        // phase B: all 8 gathers issue unconditionally (dead edges clamp to re-1, w=0 masks)
#pragma unroll
        for (int e = 0; e < 8; e++) {
            float wb = __shfl(w, e * 8 + hB, 64);
            int se = __builtin_amdgcn_readlane(s8, e * 8);
            unsigned hv = ((const unsigned*)(h1 + (size_t)se * 256))[lane];
            f32x2 lo = __builtin_amdgcn_cvt_pk_f32_fp8(hv, false);
            f32x2 hi = __builtin_amdgcn_cvt_pk_f32_fp8(hv, true);
            if (e & 1) {
                Ab.x += wb * lo[0]; Ab.y += wb * lo[1];
                Ab.z += wb * hi[0]; Ab.w += wb * hi[1];
            } else {
                Aa.x += wb * lo[0]; Aa.y += wb * lo[1];
                Aa.z += wb * hi[0]; Aa.w += wb * hi[1];
            }
        }
    }
    // reduce dsum over the 8 edge slots
    dsum += __shfl_xor(dsum, 8, 64);
    dsum += __shfl_xor(dsum, 16, 64);
    dsum += __shfl_xor(dsum, 32, 64);
    float den = __shfl(dsum, hB, 64);    // lane L<8 holds den for head L
    float4 acc = {Aa.x + Ab.x, Aa.y + Ab.y, Aa.z + Ab.z, Aa.w + Ab.w};
    const float inv = 1.0f / den;
    float4 bb = ((const float4*)b1)[lane];
    float vx = acc.x * inv + bb.x, vy = acc.y * inv + bb.y;
    float vz = acc.z * inv + bb.z, vw = acc.w * inv + bb.w;
    vx = vx > 0.f ? vx : 0.f; vy = vy > 0.f ? vy : 0.f;
    vz = vz > 0.f ? vz : 0.f; vw = vw > 0.f ? vw : 0.f;
    ushort4 o = {f2b(vx), f2b(vy), f2b(vz), f2b(vw)};
    ((ushort4*)(x2 + (size_t)n * 256))[lane] = o;
}

// ---------------- layer 2 GEMM via MFMA: h2 = x2 @ W2 (256->32), fused logits ----------------
__global__ __launch_bounds__(256) void gemm2_kernel(const unsigned short* __restrict__ x2,
                                                    const unsigned short* __restrict__ W2T,
                                                    const float* __restrict__ att_src2,
                                                    const float* __restrict__ att_dst2,
                                                    unsigned short* __restrict__ h2,
                                                    float* __restrict__ a_src2,
                                                    float* __restrict__ a_dst2) {
    const int wv = threadIdx.x >> 6;
    const int lane = threadIdx.x & 63;
    const int quad = lane >> 4, c = lane & 15;
    const int base_m = blockIdx.x * 128 + wv * 32;
    f32x4 acc[2][2] = {{{0, 0, 0, 0}, {0, 0, 0, 0}}, {{0, 0, 0, 0}, {0, 0, 0, 0}}};
#pragma unroll
    for (int ks = 0; ks < 8; ks++) {
        bf16x8 b0 = *(const bf16x8*)(W2T + (size_t)c * 256 + ks * 32 + quad * 8);
        bf16x8 b1 = *(const bf16x8*)(W2T + (size_t)(16 + c) * 256 + ks * 32 + quad * 8);
#pragma unroll
        for (int mt = 0; mt < 2; mt++) {
            int row = base_m + mt * 16 + c;
            int rowc = row < N ? row : N - 1;
            bf16x8 a = *(const bf16x8*)(x2 + (size_t)rowc * 256 + ks * 32 + quad * 8);
            acc[mt][0] = __builtin_amdgcn_mfma_f32_16x16x32_bf16(a, b0, acc[mt][0], 0, 0, 0);
            acc[mt][1] = __builtin_amdgcn_mfma_f32_16x16x32_bf16(a, b1, acc[mt][1], 0, 0, 0);
        }
    }
    float as0 = att_src2[c], as1 = att_src2[16 + c];
    float ad0 = att_dst2[c], ad1 = att_dst2[16 + c];
#pragma unroll
    for (int mt = 0; mt < 2; mt++) {
#pragma unroll
        for (int r = 0; r < 4; r++) {
            int row = base_m + mt * 16 + quad * 4 + r;
            float v0 = acc[mt][0][r], v1 = acc[mt][1][r];
            float ps = v0 * as0 + v1 * as1;
            float pd = v0 * ad0 + v1 * ad1;
#pragma unroll
            for (int off = 1; off < 16; off <<= 1) {
                ps += __shfl_xor(ps, off, 64);
                pd += __shfl_xor(pd, off, 64);
            }
            if (row < N) {
                h2[(size_t)row * 32 + c] = f2b(v0);
                h2[(size_t)row * 32 + 16 + c] = f2b(v1);
                if (c == 0) { a_src2[row] = ps; a_dst2[row] = pd; }
            }
        }
    }
}

// ---------------- layer 2 aggregate v4 + fused final: half-wave/node, 8 chains,
// exp deduplicated (lane l computes edge l&7 only; shfl broadcast) ----------------
__global__ __launch_bounds__(256) void seg2_kernel(const int* __restrict__ esrc,
                                                   const int* __restrict__ rofs,
                                                   const float* __restrict__ a_src2,
                                                   const float* __restrict__ a_dst2,
                                                   const unsigned short* __restrict__ h2,
                                                   const float* __restrict__ b2,
                                                   const float* __restrict__ linW,
                                                   const float* __restrict__ linb,
                                                   float* __restrict__ out) {
    __shared__ float lws[32 * 41];   // stride 41 breaks the 40-stride bank pattern
    __shared__ float vbuf[8][33];
    const int t = threadIdx.x;
    for (int i = t; i < 1280; i += 256) {
        int ci = i / 40, o = i - ci * 40;
        lws[ci * 41 + o] = linW[i];
    }
    const int n8 = t >> 5;
    const int c = t & 31;
    const int myk = t & 7;          // the one edge slot this lane computes exp for
    const int n = blockIdx.x * 8 + n8;      // N % 8 == 0 -> always valid
    const int rs = rofs[n], re = rofs[n + 1];
    const float ad = a_dst2[n];
    float dsum = 0.f;
    float A[8] = {0, 0, 0, 0, 0, 0, 0, 0};
    for (int j0 = rs; j0 < re; j0 += 8) {
        int sidx[8];
#pragma unroll
        for (int k = 0; k < 8; k++) {
            int j = j0 + k;
            sidx[k] = esrc[j < re ? j : re - 1];
        }
        // ONE exp per lane (edge myk); 4x dedup vs all-lanes-all-edges
        float av = a_src2[sidx[myk]];
        float myw = (j0 + myk < re) ? __expf(lrelu(av + ad)) : 0.f;
        dsum += myw;
        unsigned short hb[8];
#pragma unroll
        for (int k = 0; k < 8; k++) hb[k] = h2[(size_t)sidx[k] * 32 + c];
#pragma unroll
        for (int k = 0; k < 8; k++) {
            float w = __shfl(myw, (t & 32) + k, 64);   // broadcast within half-wave
            A[k] += w * b2f(hb[k]);
        }
    }
    // den = sum over the 8 myk groups (lanes l, l^1, l^2, l^4 span all k)
    dsum += __shfl_xor(dsum, 1, 64);
    dsum += __shfl_xor(dsum, 2, 64);
    dsum += __shfl_xor(dsum, 4, 64);
    float acc = ((A[0] + A[1]) + (A[2] + A[3])) + ((A[4] + A[5]) + (A[6] + A[7]));
    vbuf[n8][c] = acc / dsum + b2[c];
    __syncthreads();
    for (int idx = t; idx < 320; idx += 256) {
        int nn = idx / 40, o = idx - nn * 40;
        float s = linb[o];
#pragma unroll
        for (int ci = 0; ci < 32; ci++) s += vbuf[nn][ci] * lws[ci * 41 + o];
        out[(size_t)blockIdx.x * 320 + idx] = s;
    }
}

extern "C" void kernel_launch(void* const* d_in, const int* in_sizes, int n_in,
                              void* d_out, int out_size, void* d_ws, size_t ws_size,
                              hipStream_t stream) {
    const float* x0       = (const float*)d_in[0];
    const float* W1       = (const float*)d_in[1];
    const float* att_src1 = (const float*)d_in[2];
    const float* att_dst1 = (const float*)d_in[3];
    const float* b1       = (const float*)d_in[4];
    const float* W2       = (const float*)d_in[5];
    const float* att_src2 = (const float*)d_in[6];
    const float* att_dst2 = (const float*)d_in[7];
    const float* b2       = (const float*)d_in[8];
    const float* linW     = (const float*)d_in[9];
    const float* linb     = (const float*)d_in[10];
    const int*   ei       = (const int*)d_in[11];
    float* out = (float*)d_out;
    float* ws  = (float*)d_ws;

    unsigned char* h1    = (unsigned char*)ws;                   // 25.6M fp8 = 6.4M floats
    unsigned short* x2   = (unsigned short*)(ws + 6400000);      // 25.6M bf16 = 12.8M floats
    float* a_src1        = ws + 19200000;                        // 0.8M
    float* a_dst1        = ws + 20000000;                        // 0.8M
    unsigned short* h2   = (unsigned short*)(ws + 20800000);     // 3.2M bf16 = 1.6M floats
    float* a_src2        = ws + 22400000;                        // 0.1M
    float* a_dst2        = ws + 22500000;                        // 0.1M
    unsigned short* W1T  = (unsigned short*)(ws + 22600000);     // 272*128 bf16
    unsigned short* W2T  = (unsigned short*)(ws + 22620000);     // 32*256 bf16
    int*   hist          = (int*)(ws + 22630000);                // 0.1M
    int*   rofs          = (int*)(ws + 22730000);                // N+1
    int*   cursor        = (int*)(ws + 22840000);                // 0.1M
    int*   bsum          = (int*)(ws + 22940000);                // 512
    int*   esrc          = (int*)(ws + 22941000);                // 1.1M

    hipMemsetAsync(hist, 0, (size_t)N * 4, stream);

    // XCD-bucketed hist + weight prep
    prep_kernel<<<NBH + 168, 256, 0, stream>>>(ei, hist, W1, W2, att_src1, att_dst1, W1T, W2T);
    // merged gemm1 + scan1 (both depend only on prep; scan1 is atomic-free and tiny)
    g1s_kernel<<<NBG + NB1, 256, 0, stream>>>(x0, W1T, h1, a_src1, a_dst1, hist, rofs, bsum);
    // merged scan2+scan3: per-block redundant bsum prefix reduction
    scan23_kernel<<<NB1, 256, 0, stream>>>(rofs, bsum, cursor);
    // XCD-bucketed scatter: 8 blocks per edge window, bucket = blockIdx & 7
    scatter_kernel<<<NBE * 8, 256, 0, stream>>>(ei, cursor, esrc);

    seg1_kernel<<<N / 4, 256, 0, stream>>>(esrc, rofs, a_src1, a_dst1, h1, b1, x2);
    gemm2_kernel<<<(N + 127) / 128, 256, 0, stream>>>(x2, W2T, att_src2, att_dst2, h2, a_src2, a_dst2);
    seg2_kernel<<<N / 8, 256, 0, stream>>>(esrc, rofs, a_src2, a_dst2, h2, b2, linW, linb, out);
}